// Round 15
// baseline (632.984 us; speedup 1.0000x reference)
//
#include <hip/hip_runtime.h>
#include <math.h>

#define NEGV -1e9f

typedef short bf16x8 __attribute__((ext_vector_type(8)));
typedef float f32x4 __attribute__((ext_vector_type(4)));
typedef unsigned short ushort8v __attribute__((ext_vector_type(8)));

static __device__ __forceinline__ unsigned short f2bf(float f) {
  unsigned int u = __float_as_uint(f);
  unsigned int r = (u + 0x7fffu + ((u >> 16) & 1u)) >> 16;
  return (unsigned short)r;
}
static __device__ __forceinline__ float bf2f(unsigned short u) {
  return __uint_as_float((unsigned int)u << 16);
}

// bijective XCD-chunking swizzle (m204 form)
static __device__ __forceinline__ int xcd_swz(int lin, int nwg) {
  int q = nwg >> 3, r = nwg & 7;
  int x = lin & 7, i = lin >> 3;
  return (x < r) ? x * (q + 1) + i : r * (q + 1) + (x - r) * q + i;
}

// ---------------------------------------------------------------------------
// reductions
// ---------------------------------------------------------------------------
__device__ __forceinline__ float wred_max(float v) {
  #pragma unroll
  for (int o = 32; o > 0; o >>= 1) v = fmaxf(v, __shfl_down(v, o, 64));
  return v;
}
__device__ __forceinline__ float wred_sum(float v) {
  #pragma unroll
  for (int o = 32; o > 0; o >>= 1) v += __shfl_down(v, o, 64);
  return v;
}

// ---------------------------------------------------------------------------
// masked softmax over LAST dim (3-pass, R5-proven). X: (batch,R,Cn)
// ---------------------------------------------------------------------------
__global__ __launch_bounds__(256)
void softmax_row_mask(const float* __restrict__ X, const int* __restrict__ mask,
                      float* __restrict__ Y, unsigned short* __restrict__ Ybf,
                      int R, int Cn)
{
  int bz = blockIdx.y, r = blockIdx.x, tid = threadIdx.x;
  const float* xr = X + ((size_t)bz * R + r) * Cn;
  const int*   mr = mask + (size_t)bz * Cn;
  float*       yr = Y ? (Y + ((size_t)bz * R + r) * Cn) : nullptr;
  unsigned short* yb = Ybf ? (Ybf + ((size_t)bz * R + r) * Cn) : nullptr;
  __shared__ float sred[4];

  float mx = -INFINITY;
  for (int i = tid; i < Cn; i += 256) {
    float v = (mr[i] != 0) ? xr[i] : NEGV;
    mx = fmaxf(mx, v);
  }
  float wm = wred_max(mx);
  if ((tid & 63) == 0) sred[tid >> 6] = wm;
  __syncthreads();
  mx = fmaxf(fmaxf(sred[0], sred[1]), fmaxf(sred[2], sred[3]));
  __syncthreads();

  float s = 0.f;
  for (int i = tid; i < Cn; i += 256) {
    float v = (mr[i] != 0) ? xr[i] : NEGV;
    s += expf(v - mx);
  }
  float wsv = wred_sum(s);
  if ((tid & 63) == 0) sred[tid >> 6] = wsv;
  __syncthreads();
  s = sred[0] + sred[1] + sred[2] + sred[3];
  float inv = 1.0f / s;

  for (int i = tid; i < Cn; i += 256) {
    float v = (mr[i] != 0) ? xr[i] : NEGV;
    float o = expf(v - mx) * inv;
    if (yr) yr[i] = o;
    if (yb) yb[i] = f2bf(o);
  }
}

// ---------------------------------------------------------------------------
// column-softmax stats, tile-parallel. X (batch,n,n) f32, mask on ROW index.
// grid (n/64 coltiles, n/64 rowtiles, batch).
// ---------------------------------------------------------------------------
__global__ __launch_bounds__(256)
void colsm_stats(const float* __restrict__ X, const int* __restrict__ mask,
                 float* __restrict__ SM, float* __restrict__ SS, int n)
{
  int bz = blockIdx.z;
  const float* Xb = X + (size_t)bz * n * n;
  const int*   mr = mask + (size_t)bz * n;
  __shared__ float T[64][65];
  __shared__ float rm[4][64], rs[4][64];
  int j0 = blockIdx.x * 64, i0 = blockIdx.y * 64;
  int t = threadIdx.x;
  int tr = t >> 4, tc4 = (t & 15) * 4;
  int jj = t & 63, qq = t >> 6;

  #pragma unroll
  for (int r = 0; r < 4; ++r) {
    int i = tr + r * 16;
    float4 v = *reinterpret_cast<const float4*>(Xb + (size_t)(i0 + i) * n + j0 + tc4);
    int mk = mr[i0 + i];
    T[i][tc4 + 0] = mk ? v.x : NEGV;
    T[i][tc4 + 1] = mk ? v.y : NEGV;
    T[i][tc4 + 2] = mk ? v.z : NEGV;
    T[i][tc4 + 3] = mk ? v.w : NEGV;
  }
  __syncthreads();
  float m = -INFINITY, s = 0.f;
  #pragma unroll
  for (int r = 0; r < 16; ++r) {
    float v = T[qq * 16 + r][jj];
    float nm = fmaxf(m, v);
    s = s * expf(m - nm) + expf(v - nm);
    m = nm;
  }
  rm[qq][jj] = m; rs[qq][jj] = s;
  __syncthreads();
  if (t < 64) {
    float m0 = rm[0][t], m1 = rm[1][t], m2 = rm[2][t], m3 = rm[3][t];
    float fm = fmaxf(fmaxf(m0, m1), fmaxf(m2, m3));
    float fs = rs[0][t] * expf(m0 - fm) + rs[1][t] * expf(m1 - fm)
             + rs[2][t] * expf(m2 - fm) + rs[3][t] * expf(m3 - fm);
    size_t base = (((size_t)bz * gridDim.x + blockIdx.x) * gridDim.y + blockIdx.y) * 64 + t;
    SM[base] = fm; SS[base] = fs;
  }
}

// ---------------------------------------------------------------------------
// column-softmax emit, transposed bf16 output. Y[b][j][i] = colsoftmax.
// grid (n/64 coltiles, n/64 rowtiles, batch).
// ---------------------------------------------------------------------------
__global__ __launch_bounds__(256)
void colsm_emit(const float* __restrict__ X, const int* __restrict__ mask,
                const float* __restrict__ SM, const float* __restrict__ SS,
                unsigned short* __restrict__ Y, int n)
{
  int bz = blockIdx.z;
  const float* Xb = X + (size_t)bz * n * n;
  const int*   mr = mask + (size_t)bz * n;
  unsigned short* Yb = Y + (size_t)bz * n * n;
  __shared__ float T[64][65];
  __shared__ float sm[64], sinv[64];
  int j0 = blockIdx.x * 64, i0 = blockIdx.y * 64;
  int t = threadIdx.x;
  int tr = t >> 4, tc4 = (t & 15) * 4;
  int nt = gridDim.y;

  if (t < 64) {
    size_t base = (((size_t)bz * gridDim.x + blockIdx.x) * nt) * 64 + t;
    float fm = -INFINITY;
    for (int it = 0; it < nt; ++it) fm = fmaxf(fm, SM[base + (size_t)it * 64]);
    float fs = 0.f;
    for (int it = 0; it < nt; ++it)
      fs += SS[base + (size_t)it * 64] * expf(SM[base + (size_t)it * 64] - fm);
    sm[t] = fm; sinv[t] = 1.0f / fs;
  }
  #pragma unroll
  for (int r = 0; r < 4; ++r) {
    int i = tr + r * 16;
    float4 v = *reinterpret_cast<const float4*>(Xb + (size_t)(i0 + i) * n + j0 + tc4);
    int mk = mr[i0 + i];
    T[i][tc4 + 0] = mk ? v.x : NEGV;
    T[i][tc4 + 1] = mk ? v.y : NEGV;
    T[i][tc4 + 2] = mk ? v.z : NEGV;
    T[i][tc4 + 3] = mk ? v.w : NEGV;
  }
  __syncthreads();
  #pragma unroll
  for (int r = 0; r < 4; ++r) {
    int jr = tr + r * 16;
    float fm = sm[jr], inv = sinv[jr];
    ushort4 o;
    o.x = f2bf(expf(T[tc4 + 0][jr] - fm) * inv);
    o.y = f2bf(expf(T[tc4 + 1][jr] - fm) * inv);
    o.z = f2bf(expf(T[tc4 + 2][jr] - fm) * inv);
    o.w = f2bf(expf(T[tc4 + 3][jr] - fm) * inv);
    *reinterpret_cast<ushort4*>(Yb + (size_t)(j0 + jr) * n + i0 + tc4) = o;
  }
}

// ---------------------------------------------------------------------------
// batched f32 tiled transpose: X (batch, R, C) -> Y (batch, C, R)
// ---------------------------------------------------------------------------
__global__ __launch_bounds__(256)
void transp_f32(const float* __restrict__ X, float* __restrict__ Y,
                int R, int C, long sX, long sY)
{
  int bz = blockIdx.z;
  X += (size_t)bz * sX;
  Y += (size_t)bz * sY;
  __shared__ float T[64][65];
  int c0 = blockIdx.x * 64, r0 = blockIdx.y * 64;
  int t = threadIdx.x;
  int tr = t >> 4, tc4 = (t & 15) * 4;
  #pragma unroll
  for (int rr = 0; rr < 4; ++rr) {
    int r = tr + rr * 16;
    float4 v = make_float4(0.f, 0.f, 0.f, 0.f);
    if (c0 + tc4 < C)
      v = *reinterpret_cast<const float4*>(X + (size_t)(r0 + r) * C + c0 + tc4);
    T[r][tc4 + 0] = v.x; T[r][tc4 + 1] = v.y;
    T[r][tc4 + 2] = v.z; T[r][tc4 + 3] = v.w;
  }
  __syncthreads();
  #pragma unroll
  for (int rr = 0; rr < 4; ++rr) {
    int cc = tr + rr * 16;
    int gc = c0 + cc;
    if (gc < C) {
      float4 o = make_float4(T[tc4 + 0][cc], T[tc4 + 1][cc], T[tc4 + 2][cc], T[tc4 + 3][cc]);
      *reinterpret_cast<float4*>(Y + (size_t)gc * R + r0 + tc4) = o;
    }
  }
}

// ---------------------------------------------------------------------------
// bf16 square transpose (768x768 per batch)
// ---------------------------------------------------------------------------
__global__ __launch_bounds__(256)
void transp_bf16(const unsigned short* __restrict__ X, unsigned short* __restrict__ Y)
{
  int bz = blockIdx.z;
  X += (size_t)bz * 589824;
  Y += (size_t)bz * 589824;
  __shared__ unsigned short T[64][65];
  int c0 = blockIdx.x * 64, r0 = blockIdx.y * 64;
  int t = threadIdx.x;
  int tr = t >> 4, tc4 = (t & 15) * 4;
  #pragma unroll
  for (int rr = 0; rr < 4; ++rr) {
    int r = tr + rr * 16;
    ushort4 v = *reinterpret_cast<const ushort4*>(X + (size_t)(r0 + r) * 768 + c0 + tc4);
    T[r][tc4 + 0] = v.x; T[r][tc4 + 1] = v.y;
    T[r][tc4 + 2] = v.z; T[r][tc4 + 3] = v.w;
  }
  __syncthreads();
  #pragma unroll
  for (int rr = 0; rr < 4; ++rr) {
    int cc = tr + rr * 16;
    ushort4 o;
    o.x = T[tc4 + 0][cc]; o.y = T[tc4 + 1][cc];
    o.z = T[tc4 + 2][cc]; o.w = T[tc4 + 3][cc];
    *reinterpret_cast<ushort4*>(Y + (size_t)(c0 + cc) * 768 + r0 + tc4) = o;
  }
}

// ---------------------------------------------------------------------------
// transpose V: (batch, 96, 768) f32 -> VTb (batch, 768, 96) bf16
// ---------------------------------------------------------------------------
__global__ __launch_bounds__(256)
void transpV(const float* __restrict__ V, unsigned short* __restrict__ VT)
{
  int bz = blockIdx.z;
  const float* Vb = V + (size_t)bz * 96 * 768;
  unsigned short* Yb = VT + (size_t)bz * 768 * 96;
  __shared__ float T[64][65];
  int c0 = blockIdx.x * 64, r0 = blockIdx.y * 64;
  int t = threadIdx.x;
  int tr = t >> 4, tc4 = (t & 15) * 4;
  #pragma unroll
  for (int rr = 0; rr < 4; ++rr) {
    int r = tr + rr * 16;
    int gr = r0 + r;
    float4 v = make_float4(0.f, 0.f, 0.f, 0.f);
    if (gr < 96)
      v = *reinterpret_cast<const float4*>(Vb + (size_t)gr * 768 + c0 + tc4);
    T[r][tc4 + 0] = v.x; T[r][tc4 + 1] = v.y;
    T[r][tc4 + 2] = v.z; T[r][tc4 + 3] = v.w;
  }
  __syncthreads();
  #pragma unroll
  for (int rr = 0; rr < 4; ++rr) {
    int cc = tr + rr * 16;
    int gc = c0 + cc;
    #pragma unroll
    for (int e = 0; e < 4; ++e) {
      int gr = r0 + tc4 + e;
      if (gr < 96) Yb[(size_t)gc * 96 + gr] = f2bf(T[tc4 + e][cc]);
    }
  }
}

// ---------------------------------------------------------------------------
// Merged weight prep: grid (12, 48, 4).
//  by < 36: folded SFU weight z (3072x768 -> slice z of Wt (768,2304)):
//    k in [0,768): Wa+Wd ; [768,1536): Wb-Wd ; [1536,2304): Wc
//  by >= 36: small weight z (768x768 -> WuT + z*768*768), k0=(by-36)*64
// ---------------------------------------------------------------------------
__global__ __launch_bounds__(256)
void wprep(const float* __restrict__ S0, const float* __restrict__ S1,
           const float* __restrict__ S2, const float* __restrict__ S3,
           const float* __restrict__ W0, const float* __restrict__ W1a,
           const float* __restrict__ W2a, const float* __restrict__ W3a,
           unsigned short* __restrict__ Wt, unsigned short* __restrict__ WuT)
{
  int z = blockIdx.z;
  __shared__ float T[64][65];
  int n0 = blockIdx.x * 64;
  int t = threadIdx.x;
  int tr = t >> 4, tc4 = (t & 15) * 4;

  if (blockIdx.y < 36) {
    const float* W = (z == 0) ? S0 : (z == 1) ? S1 : (z == 2) ? S2 : S3;
    unsigned short* Y = Wt + (size_t)z * 768 * 2304;
    int k0 = blockIdx.y * 64;
    #pragma unroll
    for (int r = 0; r < 4; ++r) {
      int k = tr + r * 16;
      int gk = k0 + k;
      float4 v = *reinterpret_cast<const float4*>(W + (size_t)gk * 768 + n0 + tc4);
      if (gk < 768) {
        float4 u = *reinterpret_cast<const float4*>(W + (size_t)(gk + 2304) * 768 + n0 + tc4);
        v.x += u.x; v.y += u.y; v.z += u.z; v.w += u.w;
      } else if (gk < 1536) {
        float4 u = *reinterpret_cast<const float4*>(W + (size_t)(gk + 1536) * 768 + n0 + tc4);
        v.x -= u.x; v.y -= u.y; v.z -= u.z; v.w -= u.w;
      }
      T[k][tc4 + 0] = v.x; T[k][tc4 + 1] = v.y; T[k][tc4 + 2] = v.z; T[k][tc4 + 3] = v.w;
    }
    __syncthreads();
    #pragma unroll
    for (int r = 0; r < 4; ++r) {
      int n = tr + r * 16;
      ushort4 o;
      o.x = f2bf(T[tc4 + 0][n]); o.y = f2bf(T[tc4 + 1][n]);
      o.z = f2bf(T[tc4 + 2][n]); o.w = f2bf(T[tc4 + 3][n]);
      *reinterpret_cast<ushort4*>(Y + (size_t)(n0 + n) * 2304 + k0 + tc4) = o;
    }
  } else {
    const float* W = (z == 0) ? W0 : (z == 1) ? W1a : (z == 2) ? W2a : W3a;
    unsigned short* Y = WuT + (size_t)z * 768 * 768;
    int k0 = (blockIdx.y - 36) * 64;
    #pragma unroll
    for (int r = 0; r < 4; ++r) {
      int k = tr + r * 16;
      float4 v = *reinterpret_cast<const float4*>(W + (size_t)(k0 + k) * 768 + n0 + tc4);
      T[k][tc4 + 0] = v.x; T[k][tc4 + 1] = v.y; T[k][tc4 + 2] = v.z; T[k][tc4 + 3] = v.w;
    }
    __syncthreads();
    #pragma unroll
    for (int r = 0; r < 4; ++r) {
      int n = tr + r * 16;
      ushort4 o;
      o.x = f2bf(T[tc4 + 0][n]); o.y = f2bf(T[tc4 + 1][n]);
      o.z = f2bf(T[tc4 + 2][n]); o.w = f2bf(T[tc4 + 3][n]);
      *reinterpret_cast<ushort4*>(Y + (size_t)(n0 + n) * 768 + k0 + tc4) = o;
    }
  }
}

// ---------------------------------------------------------------------------
// flat f32 -> bf16 cast. n8 = elems/8.
// ---------------------------------------------------------------------------
__global__ __launch_bounds__(256)
void cast_bf16(const float* __restrict__ X, unsigned short* __restrict__ Y, int n8)
{
  int idx = blockIdx.x * 256 + threadIdx.x;
  if (idx >= n8) return;
  float4 a0 = *reinterpret_cast<const float4*>(X + (size_t)idx * 8);
  float4 a1 = *reinterpret_cast<const float4*>(X + (size_t)idx * 8 + 4);
  ushort8v o;
  o[0] = f2bf(a0.x); o[1] = f2bf(a0.y); o[2] = f2bf(a0.z); o[3] = f2bf(a0.w);
  o[4] = f2bf(a1.x); o[5] = f2bf(a1.y); o[6] = f2bf(a1.z); o[7] = f2bf(a1.w);
  *reinterpret_cast<ushort8v*>(Y + (size_t)idx * 8) = o;
}

// ===========================================================================
// Swizzled LDS layout (verified r9, conflicts -> 0):
//   staging source granule pre-swizzled (gsrc = (l&3)^((l>>3)&3)), LDS dest
//   linear; read offset prm = ((l>>4)^((l>>1)&3))*8 ushorts.
//   Direct-write mapping (row r, granule G):
//     ushort idx = (r>>4)*512 + ((r&15)*4 + (G ^ ((r>>1)&3)))*8
// R15: Mc shrunk to Mc2 = [f | x*f] (stride 1536); the x segment (K-tiles
// 0-23) is staged DIRECTLY from the activation bf16 buffer (bit-identical to
// the old copy). Activation bf16 ping-pong: XB0 (t3) = x/z, XB1 (t2) = h,
// so no kernel reads the buffer it writes.
// ===========================================================================

template<int NB, int WAVES>
__global__ __launch_bounds__(64 * WAVES)
void mfma_gemm(const unsigned short* __restrict__ A,
               const unsigned short* __restrict__ Bt0,
               const unsigned short* __restrict__ Bt1,
               const float* __restrict__ bias0, const float* __restrict__ bias1,
               const float* __restrict__ alphap, const float* __restrict__ C0,
               float* __restrict__ F0, float* __restrict__ F1,
               unsigned short* __restrict__ O0, unsigned short* __restrict__ O1,
               int M, int N, int K,
               long sA, long sB, long sC0, long sC,
               int relu, int zerodiag,
               const unsigned short* __restrict__ Xc, unsigned short* __restrict__ McO)
{
  const int RG = WAVES / 4;
  const int TM = RG * 48;
  __shared__ unsigned short As[2][TM * 32];
  __shared__ unsigned short Bs0[2][2048];
  __shared__ unsigned short Bs1[2][NB == 2 ? 2048 : 16];

  int nx = gridDim.x, ny = gridDim.y;
  int nwg = nx * ny * gridDim.z;
  int lin = blockIdx.x + nx * (blockIdx.y + ny * blockIdx.z);
  int sw = xcd_swz(lin, nwg);
  int bxi = sw % nx; int rest = sw / nx;
  int byi = rest % ny; int bz = rest / ny;

  A   += (size_t)bz * sA;
  Bt0 += (size_t)bz * sB;
  if (NB == 2) Bt1 += (size_t)bz * sB;
  const float* C0b = C0 ? (C0 + (size_t)bz * sC0) : nullptr;

  int tid = threadIdx.x;
  int w = tid >> 6, l = tid & 63;
  int m0 = byi * TM, n0 = bxi * 64;
  int wr = w >> 2, wc = w & 3;

  int g8 = (((l & 3) ^ ((l >> 3) & 3))) * 8;
  int rowA = w * 16 + (l >> 2); if (rowA > TM - 1) rowA = TM - 1;
  int rB = n0 + (w & 3) * 16 + (l >> 2); if (rB > N - 1) rB = N - 1;
  const unsigned short* srcA  = A + (size_t)(m0 + rowA) * K + g8;
  const unsigned short* srcB0 = Bt0 + (size_t)rB * K + g8;
  const unsigned short* srcB1 = (NB == 2) ? Bt1 + (size_t)rB * K + g8 : nullptr;

#define GG_STAGE(kt, bi) do { int kk0 = (kt) * 32;                                                                        \
    if (w < TM / 16)                                                                                                      \
      __builtin_amdgcn_global_load_lds((const unsigned int*)(srcA + kk0),  (unsigned int*)&As[bi][0]  + w * 256, 16, 0, 0); \
    if (w < 4)                                                                                                            \
      __builtin_amdgcn_global_load_lds((const unsigned int*)(srcB0 + kk0), (unsigned int*)&Bs0[bi][0] + w * 256, 16, 0, 0); \
    if (NB == 2 && w >= 4)                                                                                                \
      __builtin_amdgcn_global_load_lds((const unsigned int*)(srcB1 + kk0), (unsigned int*)&Bs1[bi][0] + (w - 4) * 256, 16, 0, 0); \
  } while (0)

  f32x4 a0[3] = {};
  f32x4 a1v[3] = {};

  const int NT = K / 32;
  int prm = ((l >> 4) ^ ((l >> 1) & 3)) * 8;
  GG_STAGE(0, 0);
  __syncthreads();
  int cur = 0;
  for (int kt = 0; kt < NT; ++kt) {
    if (kt + 1 < NT) GG_STAGE(kt + 1, cur ^ 1);

    bf16x8 af[3];
    #pragma unroll
    for (int i = 0; i < 3; ++i) {
      int off = (wr * 48 + i * 16 + (l & 15)) * 32 + prm;
      af[i] = *reinterpret_cast<const bf16x8*>(&As[cur][off]);
    }
    int offB = (wc * 16 + (l & 15)) * 32 + prm;
    bf16x8 b0 = *reinterpret_cast<const bf16x8*>(&Bs0[cur][offB]);
    #pragma unroll
    for (int i = 0; i < 3; ++i)
      a0[i] = __builtin_amdgcn_mfma_f32_16x16x32_bf16(af[i], b0, a0[i], 0, 0, 0);
    if (NB == 2) {
      bf16x8 b1 = *reinterpret_cast<const bf16x8*>(&Bs1[cur][offB]);
      #pragma unroll
      for (int i = 0; i < 3; ++i)
        a1v[i] = __builtin_amdgcn_mfma_f32_16x16x32_bf16(af[i], b1, a1v[i], 0, 0, 0);
    }
    __syncthreads();
    cur ^= 1;
  }
#undef GG_STAGE

  float alpha = alphap ? alphap[0] : 1.0f;
  float* F0b = F0 ? F0 + (size_t)bz * sC : nullptr;
  float* F1b = F1 ? F1 + (size_t)bz * sC : nullptr;
  unsigned short* O0b = O0 ? O0 + (size_t)bz * sC : nullptr;
  unsigned short* O1b = O1 ? O1 + (size_t)bz * sC : nullptr;
  const unsigned short* Xcb = Xc ? Xc + (size_t)bz * 589824 : nullptr;
  unsigned short* Mcb = McO ? McO + (size_t)bz * 1179648 : nullptr;   // 768*1536

  #pragma unroll
  for (int i = 0; i < 3; ++i) {
    #pragma unroll
    for (int qq = 0; qq < 4; ++qq) {
      int gm = m0 + wr * 48 + i * 16 + (l >> 4) * 4 + qq;
      int gn = n0 + wc * 16 + (l & 15);
      if (gn >= N) continue;
      size_t oidx = (size_t)gm * N + gn;
      float v = alpha * a0[i][qq];
      if (bias0) v += bias0[gn];
      if (relu) v = fmaxf(v, 0.f);
      if (C0b) v += C0b[oidx];
      if (zerodiag && gm == gn) v = 0.f;
      if (Mcb) {
        float xv = bf2f(Xcb[(size_t)gm * 768 + gn]);
        size_t mrow = (size_t)gm * 1536 + gn;
        Mcb[mrow]        = f2bf(v);
        Mcb[mrow + 768]  = f2bf(xv * v);
      }
      if (F0b) F0b[oidx] = v;
      if (O0b) O0b[oidx] = f2bf(v);
      if (NB == 2) {
        float v1 = alpha * a1v[i][qq];
        if (bias1) v1 += bias1[gn];
        if (relu) v1 = fmaxf(v1, 0.f);
        if (F1b) F1b[oidx] = v1;
        if (O1b) O1b[oidx] = f2bf(v1);
      }
    }
  }
}

// ---------------------------------------------------------------------------
// Merged step-1 + step-2 relu-GEMM pair (both K=768, N=768, TM=96, bf16 out).
// grid (12, 72): byi<64 -> GEMM1 (M=6144), byi>=64 -> GEMM2 (M=768).
// ---------------------------------------------------------------------------
__global__ __launch_bounds__(512)
void mfma_relu_pair(const unsigned short* __restrict__ A1g,
                    const unsigned short* __restrict__ B1g,
                    const float* __restrict__ bias1g, unsigned short* __restrict__ O1g,
                    const unsigned short* __restrict__ A2g,
                    const unsigned short* __restrict__ B2g,
                    const float* __restrict__ bias2g, unsigned short* __restrict__ O2g)
{
  const int K = 768, N = 768, NT = 24;
  __shared__ unsigned short As[2][3072];
  __shared__ unsigned short Bs0[2][2048];

  int nx = gridDim.x, ny = gridDim.y;
  int nwg = nx * ny;
  int lin = blockIdx.x + nx * blockIdx.y;
  int sw = xcd_swz(lin, nwg);
  int bxi = sw % nx; int byi = sw / nx;

  const unsigned short* A; const unsigned short* Bt;
  const float* bias; unsigned short* O;
  int m0;
  if (byi < 64) { A = A1g; Bt = B1g; bias = bias1g; O = O1g; m0 = byi * 96; }
  else          { A = A2g; Bt = B2g; bias = bias2g; O = O2g; m0 = (byi - 64) * 96; }

  int tid = threadIdx.x;
  int w = tid >> 6, l = tid & 63;
  int n0 = bxi * 64;
  int wr = w >> 2, wc = w & 3;

  int g8 = (((l & 3) ^ ((l >> 3) & 3))) * 8;
  int rowA = w * 16 + (l >> 2); if (rowA > 95) rowA = 95;  // w<6 only
  int rB = n0 + (w & 3) * 16 + (l >> 2);
  const unsigned short* srcA  = A + (size_t)(m0 + rowA) * K + g8;
  const unsigned short* srcB0 = Bt + (size_t)rB * K + g8;

#define RP_STAGE(kt, bi) do { int kk0 = (kt) * 32;                                                                        \
    if (w < 6)                                                                                                            \
      __builtin_amdgcn_global_load_lds((const unsigned int*)(srcA + kk0),  (unsigned int*)&As[bi][0]  + w * 256, 16, 0, 0); \
    if (w < 4)                                                                                                            \
      __builtin_amdgcn_global_load_lds((const unsigned int*)(srcB0 + kk0), (unsigned int*)&Bs0[bi][0] + w * 256, 16, 0, 0); \
  } while (0)

  f32x4 a0[3] = {};
  int prm = ((l >> 4) ^ ((l >> 1) & 3)) * 8;
  RP_STAGE(0, 0);
  __syncthreads();
  int cur = 0;
  for (int kt = 0; kt < NT; ++kt) {
    if (kt + 1 < NT) RP_STAGE(kt + 1, cur ^ 1);

    bf16x8 af[3];
    #pragma unroll
    for (int i = 0; i < 3; ++i) {
      int off = (wr * 48 + i * 16 + (l & 15)) * 32 + prm;
      af[i] = *reinterpret_cast<const bf16x8*>(&As[cur][off]);
    }
    int offB = (wc * 16 + (l & 15)) * 32 + prm;
    bf16x8 b0 = *reinterpret_cast<const bf16x8*>(&Bs0[cur][offB]);
    #pragma unroll
    for (int i = 0; i < 3; ++i)
      a0[i] = __builtin_amdgcn_mfma_f32_16x16x32_bf16(af[i], b0, a0[i], 0, 0, 0);
    __syncthreads();
    cur ^= 1;
  }
#undef RP_STAGE

  #pragma unroll
  for (int i = 0; i < 3; ++i) {
    #pragma unroll
    for (int qq = 0; qq < 4; ++qq) {
      int gm = m0 + wr * 48 + i * 16 + (l >> 4) * 4 + qq;
      int gn = n0 + wc * 16 + (l & 15);
      float v = a0[i][qq] + bias[gn];
      v = fmaxf(v, 0.f);
      O[(size_t)gm * N + gn] = f2bf(v);
    }
  }
}

// ---------------------------------------------------------------------------
// Fused step-5 + step-6: qctx = rowsoftmax_mask(E) @ V, Mc2-concat epilogue
// (writes [f | x*f], stride 1536; x read from Xb16). grid (12,8,b), 512 thr.
// ---------------------------------------------------------------------------
__global__ __launch_bounds__(512)
void qctx_fused(const float* __restrict__ E, const int* __restrict__ Vm,
                const unsigned short* __restrict__ VTb,
                const unsigned short* __restrict__ Xb16, unsigned short* __restrict__ Mc)
{
  __shared__ unsigned short As3[3][3072];
  __shared__ unsigned short Bs3[3][2048];
  __shared__ int mk[96];

  int nx = gridDim.x, ny = gridDim.y;
  int nwg = nx * ny * gridDim.z;
  int lin = blockIdx.x + nx * (blockIdx.y + ny * blockIdx.z);
  int sw = xcd_swz(lin, nwg);
  int bxi = sw % nx; int rest = sw / nx;
  int byi = rest % ny; int bz = rest / ny;

  int tid = threadIdx.x;
  int w = tid >> 6, l = tid & 63;
  int m0 = byi * 96, n0 = bxi * 64;

  int g8 = (((l & 3) ^ ((l >> 3) & 3))) * 8;
  if (w < 4) {
    int rB = n0 + w * 16 + (l >> 2);
    const unsigned short* srcB = VTb + ((size_t)bz * 768 + rB) * 96 + g8;
    #pragma unroll
    for (int kt = 0; kt < 3; ++kt)
      __builtin_amdgcn_global_load_lds((const unsigned int*)(srcB + kt * 32),
                                       (unsigned int*)&Bs3[kt][0] + w * 256, 16, 0, 0);
  }
  if (tid < 96) mk[tid] = Vm[bz * 96 + tid];
  __syncthreads();

  if (tid < 384) {
    int r = tid >> 2, j4 = tid & 3;
    const float* er = E + ((size_t)bz * 768 + m0 + r) * 96 + j4 * 24;
    float va[24];
    #pragma unroll
    for (int u = 0; u < 6; ++u) {
      float4 v = *reinterpret_cast<const float4*>(er + u * 4);
      int kb = j4 * 24 + u * 4;
      va[u * 4 + 0] = mk[kb + 0] ? v.x : NEGV;
      va[u * 4 + 1] = mk[kb + 1] ? v.y : NEGV;
      va[u * 4 + 2] = mk[kb + 2] ? v.z : NEGV;
      va[u * 4 + 3] = mk[kb + 3] ? v.w : NEGV;
    }
    float mx = -INFINITY;
    #pragma unroll
    for (int u = 0; u < 24; ++u) mx = fmaxf(mx, va[u]);
    mx = fmaxf(mx, __shfl_xor(mx, 1, 64));
    mx = fmaxf(mx, __shfl_xor(mx, 2, 64));
    float s = 0.f;
    #pragma unroll
    for (int u = 0; u < 24; ++u) { va[u] = expf(va[u] - mx); s += va[u]; }
    s += __shfl_xor(s, 1, 64);
    s += __shfl_xor(s, 2, 64);
    float inv = 1.0f / s;
    #pragma unroll
    for (int g = 0; g < 3; ++g) {
      int gG = j4 * 3 + g;
      int kt = gG >> 2, Gin = gG & 3;
      ushort8v o;
      #pragma unroll
      for (int e = 0; e < 8; ++e) o[e] = f2bf(va[g * 8 + e] * inv);
      int idx = (r >> 4) * 512 + ((r & 15) * 4 + (Gin ^ ((r >> 1) & 3))) * 8;
      *reinterpret_cast<ushort8v*>(&As3[kt][idx]) = o;
    }
  }
  __syncthreads();

  int wr = w >> 2, wc = w & 3;
  int prm = ((l >> 4) ^ ((l >> 1) & 3)) * 8;
  f32x4 acc[3] = {};
  #pragma unroll
  for (int kt = 0; kt < 3; ++kt) {
    bf16x8 af[3];
    #pragma unroll
    for (int i = 0; i < 3; ++i) {
      int off = (wr * 48 + i * 16 + (l & 15)) * 32 + prm;
      af[i] = *reinterpret_cast<const bf16x8*>(&As3[kt][off]);
    }
    int offB = (wc * 16 + (l & 15)) * 32 + prm;
    bf16x8 b0 = *reinterpret_cast<const bf16x8*>(&Bs3[kt][offB]);
    #pragma unroll
    for (int i = 0; i < 3; ++i)
      acc[i] = __builtin_amdgcn_mfma_f32_16x16x32_bf16(af[i], b0, acc[i], 0, 0, 0);
  }

  const unsigned short* Xb = Xb16 + (size_t)bz * 589824;
  unsigned short* Mcb = Mc + (size_t)bz * 1179648;
  #pragma unroll
  for (int i = 0; i < 3; ++i) {
    #pragma unroll
    for (int qq = 0; qq < 4; ++qq) {
      int gm = m0 + wr * 48 + i * 16 + (l >> 4) * 4 + qq;
      int gn = n0 + wc * 16 + (l & 15);
      float v = acc[i][qq];
      float xv = bf2f(Xb[(size_t)gm * 768 + gn]);
      size_t mrow = (size_t)gm * 1536 + gn;
      Mcb[mrow]        = f2bf(v);
      Mcb[mrow + 768]  = f2bf(xv * v);
    }
  }
}

// ---------------------------------------------------------------------------
// Fused dual-PRODUCT GEMM (8-wave): F0 = A1@B1t^T + alpha*(A2@B2t^T).
// ---------------------------------------------------------------------------
__global__ __launch_bounds__(512)
void mfma_dual2(const unsigned short* __restrict__ A1,
                const unsigned short* __restrict__ B1t,
                const unsigned short* __restrict__ A2,
                const unsigned short* __restrict__ B2t,
                const float* __restrict__ alphap, float* __restrict__ F0,
                int M, int N, int K,
                long sA1, long sB1, long sA2, long sB2, long sC,
                int zerodiag)
{
  __shared__ unsigned short As1[2][3072], Bs1[2][2048];
  __shared__ unsigned short As2[2][3072], Bs2[2][2048];

  int nx = gridDim.x, ny = gridDim.y;
  int nwg = nx * ny * gridDim.z;
  int lin = blockIdx.x + nx * (blockIdx.y + ny * blockIdx.z);
  int sw = xcd_swz(lin, nwg);
  int bxi = sw % nx; int rest = sw / nx;
  int byi = rest % ny; int bz = rest / ny;

  A1  += (size_t)bz * sA1;
  B1t += (size_t)bz * sB1;
  A2  += (size_t)bz * sA2;
  B2t += (size_t)bz * sB2;

  int tid = threadIdx.x;
  int w = tid >> 6, l = tid & 63;
  int m0 = byi * 96, n0 = bxi * 64;
  int wr = w >> 2, wc = w & 3;

  int g8 = (((l & 3) ^ ((l >> 3) & 3))) * 8;
  int rowA = w * 16 + (l >> 2); if (rowA > 95) rowA = 95;   // w<6 only
  int rB = n0 + (w & 3) * 16 + (l >> 2);
  const unsigned short* srcA1 = A1 + (size_t)(m0 + rowA) * K + g8;
  const unsigned short* srcA2 = A2 + (size_t)(m0 + rowA) * K + g8;
  const unsigned short* srcB1 = B1t + (size_t)rB * K + g8;   // w<4
  const unsigned short* srcB2 = B2t + (size_t)rB * K + g8;   // w>=4

#define D2_STAGE(kt, bi) do { int kk0 = (kt) * 32;                                                                        \
    if (w < 6) {                                                                                                          \
      __builtin_amdgcn_global_load_lds((const unsigned int*)(srcA1 + kk0), (unsigned int*)&As1[bi][0] + w * 256, 16, 0, 0); \
      __builtin_amdgcn_global_load_lds((const unsigned int*)(srcA2 + kk0), (unsigned int*)&As2[bi][0] + w * 256, 16, 0, 0); \
    }                                                                                                                     \
    if (w < 4)                                                                                                            \
      __builtin_amdgcn_global_load_lds((const unsigned int*)(srcB1 + kk0), (unsigned int*)&Bs1[bi][0] + w * 256, 16, 0, 0); \
    else                                                                                                                  \
      __builtin_amdgcn_global_load_lds((const unsigned int*)(srcB2 + kk0), (unsigned int*)&Bs2[bi][0] + (w - 4) * 256, 16, 0, 0); \
  } while (0)

  f32x4 ac1[3] = {};
  f32x4 ac2[3] = {};

  const int NT = K / 32;
  int prm = ((l >> 4) ^ ((l >> 1) & 3)) * 8;
  D2_STAGE(0, 0);
  __syncthreads();
  int cur = 0;
  for (int kt = 0; kt < NT; ++kt) {
    if (kt + 1 < NT) D2_STAGE(kt + 1, cur ^ 1);

    int offB = (wc * 16 + (l & 15)) * 32 + prm;
    bf16x8 af1[3], af2[3];
    #pragma unroll
    for (int i = 0; i < 3; ++i) {
      int off = (wr * 48 + i * 16 + (l & 15)) * 32 + prm;
      af1[i] = *reinterpret_cast<const bf16x8*>(&As1[cur][off]);
      af2[i] = *reinterpret_cast<const bf16x8*>(&As2[cur][off]);
    }
    bf16x8 b1 = *reinterpret_cast<const bf16x8*>(&Bs1[cur][offB]);
    bf16x8 b2 = *reinterpret_cast<const bf16x8*>(&Bs2[cur][offB]);
    #pragma unroll
    for (int i = 0; i < 3; ++i) {
      ac1[i] = __builtin_amdgcn_mfma_f32_16x16x32_bf16(af1[i], b1, ac1[i], 0, 0, 0);
      ac2[i] = __builtin_amdgcn_mfma_f32_16x16x32_bf16(af2[i], b2, ac2[i], 0, 0, 0);
    }
    __syncthreads();
    cur ^= 1;
  }
#undef D2_STAGE

  float alpha = alphap[0];
  float* F0b = F0 + (size_t)bz * sC;
  #pragma unroll
  for (int i = 0; i < 3; ++i) {
    #pragma unroll
    for (int qq = 0; qq < 4; ++qq) {
      int gm = m0 + wr * 48 + i * 16 + (l >> 4) * 4 + qq;
      int gn = n0 + wc * 16 + (l & 15);
      float v = ac1[i][qq] + alpha * ac2[i][qq];
      if (zerodiag && gm == gn) v = 0.f;
      F0b[(size_t)gm * N + gn] = v;
    }
  }
}

// ---------------------------------------------------------------------------
// 4-wave dual-product GEMM, TM=48, N clamped (for E = E0 + gi*Btt@Es, N=96).
// grid (ceil(N/64), M/48, batch), 256 thr.
// ---------------------------------------------------------------------------
__global__ __launch_bounds__(256)
void mfma_dualE(const unsigned short* __restrict__ A1,
                const unsigned short* __restrict__ B1t,
                const unsigned short* __restrict__ A2,
                const unsigned short* __restrict__ B2t,
                const float* __restrict__ alphap, float* __restrict__ F0,
                int M, int N, int K1, int K2,
                long sA1, long sB1, long sA2, long sB2, long sC)
{
  __shared__ unsigned short As1[2][1536], Bs1[2][2048];
  __shared__ unsigned short As2[2][1536], Bs2[2][2048];

  int nx = gridDim.x, ny = gridDim.y;
  int nwg = nx * ny * gridDim.z;
  int lin = blockIdx.x + nx * (blockIdx.y + ny * blockIdx.z);
  int sw = xcd_swz(lin, nwg);
  int bxi = sw % nx; int rest = sw / nx;
  int byi = rest % ny; int bz = rest / ny;

  A1  += (size_t)bz * sA1;
  B1t += (size_t)bz * sB1;
  A2  += (size_t)bz * sA2;
  B2t += (size_t)bz * sB2;

  int tid = threadIdx.x;
  int w = tid >> 6, l = tid & 63;
  int m0 = byi * 48, n0 = bxi * 64;

  int g8 = (((l & 3) ^ ((l >> 3) & 3))) * 8;
  int rowA = w * 16 + (l >> 2); if (rowA > 47) rowA = 47;   // w<3 only
  int rB = n0 + w * 16 + (l >> 2); if (rB > N - 1) rB = N - 1;
  const unsigned short* srcA1 = A1 + (size_t)(m0 + rowA) * K1 + g8;
  const unsigned short* srcA2 = A2 + (size_t)(m0 + rowA) * K2 + g8;
  const unsigned short* srcB1 = B1t + (size_t)rB * K1 + g8;
  const unsigned short* srcB2 = B2t + (size_t)rB * K2 + g8;

#define DE_STAGE(kt, bi) do { int kk0 = (kt) * 32;                                                                        \
    if (w < 3) {                                                                                                          \
      __builtin_amdgcn_global_load_lds((const unsigned int*)(srcA1 + kk0), (unsigned int*)&As1[bi][0] + w * 256, 16, 0, 0); \
      __builtin_amdgcn_global_load_lds((const unsigned int*)(srcA2 + kk0), (unsigned int*)&As2[bi][0] + w * 256, 16, 0, 0); \
    }                                                                                                                     \
    __builtin_amdgcn_global_load_lds((const unsigned int*)(srcB1 + kk0), (unsigned int*)&Bs1[bi][0] + w * 256, 16, 0, 0);   \
    __builtin_amdgcn_global_load_lds((const unsigned int*)(srcB2 + kk0), (unsigned int*)&Bs2[bi][0] + w * 256, 16, 0, 0);   \
  } while (0)

  f32x4 ac1[3] = {};
  f32x4 ac2[3] = {};

  const int NT = K1 / 32;   // K1 == K2 at the call site (768)
  int prm = ((l >> 4) ^ ((l >> 1) & 3)) * 8;
  DE_STAGE(0, 0);
  __syncthreads();
  int cur = 0;
  for (int kt = 0; kt < NT; ++kt) {
    if (kt + 1 < NT) DE_STAGE(kt + 1, cur ^ 1);

    int offB = (w * 16 + (l & 15)) * 32 + prm;
    bf16x8 af1[3], af2[3];
    #pragma unroll
    for (int i = 0; i < 3; ++i) {
      int off = (i * 16 + (l & 15)) * 32 + prm;
      af1[i] = *reinterpret_cast<const bf16x8*>(&As1[cur][off]);
      af2[i] = *reinterpret_cast<const bf16x8*>(&As2[cur][off]);
    }
    bf16x8 b1 = *reinterpret_cast<const bf16x8*>(&Bs1[cur][offB]);
    bf16x8 b2 = *reinterpret_cast<const bf16x8*>(&Bs2[cur][offB]);
    #pragma unroll
    for (int i = 0; i < 3; ++i) {
      ac1[i] = __builtin_amdgcn_mfma_f32_16x16x32_bf16(af1[i], b1, ac1[i], 0, 0, 0);
      ac2[i] = __builtin_amdgcn_mfma_f32_16x16x32_bf16(af2[i], b2, ac2[i], 0, 0, 0);
    }
    __syncthreads();
    cur ^= 1;
  }
#undef DE_STAGE

  float alpha = alphap[0];
  float* F0b = F0 + (size_t)bz * sC;
  #pragma unroll
  for (int i = 0; i < 3; ++i) {
    #pragma unroll
    for (int qq = 0; qq < 4; ++qq) {
      int gm = m0 + i * 16 + (l >> 4) * 4 + qq;
      int gn = n0 + w * 16 + (l & 15);
      if (gn >= N) continue;
      float v = ac1[i][qq] + alpha * ac2[i][qq];
      F0b[(size_t)gm * N + gn] = v;
    }
  }
}

// ---------------------------------------------------------------------------
// Fused dual-B MFMA SFU GEMM, 96x64 tile, double-buffered, swizzled LDS,
// 512 thr / 8 waves (2x4, wave tile 48x16 -- R5-proven), XCD-chunked blocks.
// grid (12, 64) = 768 wg. K=2304 logical: kt<24 sources rows from Xseg
// (bf16 activation, stride 768 -- bit-identical to the old copied segment),
// kt>=24 from Mc2 (stride 1536 = [f | x*f]).
// ---------------------------------------------------------------------------
__global__ __launch_bounds__(512)
void sfu_mfma(const unsigned short* __restrict__ Mc2,
              const unsigned short* __restrict__ Xseg,
              const unsigned short* __restrict__ Brt,
              const unsigned short* __restrict__ Bgt,
              const float* __restrict__ Xres, float* __restrict__ Z,
              unsigned short* __restrict__ Zb)
{
  __shared__ unsigned short As[2][3072];
  __shared__ unsigned short Brs[2][2048];
  __shared__ unsigned short Bgs[2][2048];
  const int K = 2304;
  const int NT = 72;

  int nx = gridDim.x, ny = gridDim.y;
  int nwg = nx * ny;
  int lin = blockIdx.x + nx * blockIdx.y;
  int sw = xcd_swz(lin, nwg);
  int bxi = sw % nx; int byi = sw / nx;

  int tid = threadIdx.x;
  int w = tid >> 6, l = tid & 63;
  int m0 = byi * 96, n0 = bxi * 64;
  int wr = w >> 2, wc = w & 3;

  int g8 = (((l & 3) ^ ((l >> 3) & 3))) * 8;
  int rowA = w * 16 + (l >> 2); if (rowA > 95) rowA = 95;   // used only by w<6
  int rB = n0 + (w & 3) * 16 + (l >> 2);
  const unsigned short* srcX = Xseg + (size_t)(m0 + rowA) * 768 + g8;   // kt<24
  const unsigned short* srcM = Mc2  + (size_t)(m0 + rowA) * 1536 + g8;  // kt>=24
  const unsigned short* srcR = Brt + (size_t)rB * K + g8;   // w<4
  const unsigned short* srcG = Bgt + (size_t)rB * K + g8;   // w>=4

#define SFU_STAGE(kt, bi) do {                                                                                           \
    const unsigned short* aptr = ((kt) < 24) ? (srcX + (kt) * 32) : (srcM + ((kt) - 24) * 32);                           \
    int kk0 = (kt) * 32;                                                                                                 \
    if (w < 6)                                                                                                           \
      __builtin_amdgcn_global_load_lds((const unsigned int*)aptr, (unsigned int*)&As[bi][0]  + w * 256, 16, 0, 0);        \
    if (w < 4)                                                                                                           \
      __builtin_amdgcn_global_load_lds((const unsigned int*)(srcR + kk0), (unsigned int*)&Brs[bi][0] + w * 256, 16, 0, 0); \
    if (w >= 4)                                                                                                          \
      __builtin_amdgcn_global_load_lds((const unsigned int*)(srcG + kk0), (unsigned int*)&Bgs[bi][0] + (w - 4) * 256, 16, 0, 0); \
  } while (0)

  f32x4 aR[3] = {};
  f32x4 aG[3] = {};

  int prm = ((l >> 4) ^ ((l >> 1) & 3)) * 8;
  SFU_STAGE(0, 0);
  __syncthreads();
  int cur = 0;
  for (int kt = 0; kt < NT; ++kt) {
    if (kt + 1 < NT) SFU_STAGE(kt + 1, cur ^ 1);

    bf16x8 af[3];
    #pragma unroll
    for (int i = 0; i < 3; ++i) {
      int off = (wr * 48 + i * 16 + (l & 15)) * 32 + prm;
      af[i] = *reinterpret_cast<const bf16x8*>(&As[cur][off]);
    }
    int offB = (wc * 16 + (l & 15)) * 32 + prm;
    bf16x8 br = *reinterpret_cast<const bf16x8*>(&Brs[cur][offB]);
    bf16x8 bg = *reinterpret_cast<const bf16x8*>(&Bgs[cur][offB]);
    #pragma unroll
    for (int i = 0; i < 3; ++i) {
      aR[i] = __builtin_amdgcn_mfma_f32_16x16x32_bf16(af[i], br, aR[i], 0, 0, 0);
      aG[i] = __builtin_amdgcn_mfma_f32_16x16x32_bf16(af[i], bg, aG[i], 0, 0, 0);
    }
    __syncthreads();
    cur ^= 1;
  }
#undef SFU_STAGE

  #pragma unroll
  for (int i = 0; i < 3; ++i) {
    #pragma unroll
    for (int qq = 0; qq < 4; ++qq) {
      int gm = m0 + wr * 48 + i * 16 + (l >> 4) * 4 + qq;
      int gn = n0 + wc * 16 + (l & 15);
      float r = fmaxf(aR[i][qq], 0.f);
      float g = 1.0f / (1.0f + expf(-aG[i][qq]));
      float xv = Xres[(size_t)gm * 768 + gn];
      float z = r * g + (1.0f - g) * xv;
      Z[(size_t)gm * 768 + gn] = z;
      if (Zb) Zb[(size_t)gm * 768 + gn] = f2bf(z);
    }
  }
}

// ---------------------------------------------------------------------------
// host side
// ---------------------------------------------------------------------------
static void launch_mfma1(const unsigned short* A, const unsigned short* Bt,
                         const float* bias, const float* alphap, const float* C0,
                         float* F0, unsigned short* O0,
                         int M, int N, int K, long sA, long sB, long sC0, long sC,
                         int relu, int zd, int batch, int tm, hipStream_t s,
                         const unsigned short* xcat = nullptr, unsigned short* mco = nullptr)
{
  dim3 g((N + 63) / 64, M / tm, batch);
  if (tm == 48)
    mfma_gemm<1, 4><<<g, 256, 0, s>>>(A, Bt, nullptr, bias, nullptr, alphap, C0,
                                      F0, nullptr, O0, nullptr, M, N, K, sA, sB, sC0, sC, relu, zd,
                                      xcat, mco);
  else
    mfma_gemm<1, 8><<<g, 512, 0, s>>>(A, Bt, nullptr, bias, nullptr, alphap, C0,
                                      F0, nullptr, O0, nullptr, M, N, K, sA, sB, sC0, sC, relu, zd,
                                      xcat, mco);
}

static void launch_mfma2(const unsigned short* A, const unsigned short* Bt0,
                         const unsigned short* Bt1, const float* bias0, const float* bias1,
                         unsigned short* O0, unsigned short* O1,
                         int M, int N, int K, long sA, long sB,
                         int relu, int batch, hipStream_t s)
{
  dim3 g((N + 63) / 64, M / 96, batch);
  mfma_gemm<2, 8><<<g, 512, 0, s>>>(A, Bt0, Bt1, bias0, bias1, nullptr, nullptr,
                                    nullptr, nullptr, O0, O1, M, N, K, sA, sB, 0, sA,
                                    relu, 0, nullptr, nullptr);
}

extern "C" void kernel_launch(void* const* d_in, const int* in_sizes, int n_in,
                              void* d_out, int out_size, void* d_ws, size_t ws_size,
                              hipStream_t stream)
{
  const int b = 8, c = 768, q = 96, d = 768, T = 2;
  const float* U   = (const float*)d_in[0];
  const float* V   = (const float*)d_in[1];
  const int*   Um  = (const int*)d_in[2];
  const int*   Vm  = (const int*)d_in[3];
  const float* Wu  = (const float*)d_in[4];
  const float* bu  = (const float*)d_in[5];
  const float* Wv  = (const float*)d_in[6];
  const float* bv  = (const float*)d_in[7];
  const float* Wri = (const float*)d_in[8];
  const float* Wgi = (const float*)d_in[9];
  const float* gi  = (const float*)d_in[10];
  const float* W1  = (const float*)d_in[11];
  const float* b1  = (const float*)d_in[12];
  const float* W2  = (const float*)d_in[13];
  const float* b2  = (const float*)d_in[14];
  const float* Wrs = (const float*)d_in[15];
  const float* Wgs = (const float*)d_in[16];
  const float* gs  = (const float*)d_in[17];
  float* out = (float*)d_out;

  const size_t big = (size_t)b * c * d;   // 4718592 == b*c*c
  const size_t smE = (size_t)b * c * q;   // 589824 == b*q*d
  float* ws   = (float*)d_ws;
  float* xbuf = ws + 0 * big;
  float* h    = ws + 1 * big;
  float* Bm   = ws + 2 * big;
  float* t1   = ws + 3 * big;             // Mc2 bf16 (6144x1536) / H1b+H2b bf16
  float* t2   = ws + 4 * big;             // XB1 bf16 (h)
  float* t3   = ws + 5 * big;             // XB0 bf16 (x/z) + t3h2 (Btt)
  float* t4   = ws + 6 * big;             // SFU Wt bf16 (4 slices, 14.2 MB)
  float* Ebuf = ws + 7 * big;             // persistent E (b,c,q)
  float* E0b  = Ebuf + smE;               // (unused)
  float* Esb  = E0b + smE;                // E^T f32 scratch
  float* spare = Esb + smE;               // colsm stats
  float* slotE = spare + smE;             // big/2 f32: B1sT b16 / hTb16
  float* WTf  = slotE + big / 2;          // weight + activation bf16 region

  unsigned short* Mc2 = (unsigned short*)t1;           // 6144x1536 bf16 (= t1)
  unsigned short* Wt  = (unsigned short*)t4;           // SFU weights bf16 (4 folded slices)
  unsigned short* t1h = (unsigned short*)t1;           // H1b home
  unsigned short* XB0 = (unsigned short*)t3;           // x / z bf16
  unsigned short* XB1 = (unsigned short*)t2;           // h bf16
  unsigned short* t3h2 = XB0 + big;                    // Btt bf16 (persists)
  unsigned short* slotEb = (unsigned short*)slotE;     // B1sT bf16 / hT bf16
  unsigned short* H1b = t1h;
  unsigned short* H2b = H1b + big;
  float* SMst = spare;                                 // 8*12*12*64 floats
  float* SSst = spare + 73728;
  unsigned short* WuT = (unsigned short*)WTf;
  unsigned short* WvT  = WuT  + (size_t)d * d;
  unsigned short* W1T  = WvT  + (size_t)d * d;
  unsigned short* W2T  = W1T  + (size_t)d * d;
  unsigned short* Vb16 = W2T  + (size_t)d * d;         // (b*q, d) bf16
  unsigned short* Qtbb = Vb16 + smE;                   // (b, q, d) bf16
  unsigned short* VTb  = Qtbb + smE;                   // (b, d, q) bf16
  unsigned short* EsTb = VTb  + smE;                   // (b, q, c) bf16

  const long cd = (long)c * d, cq = (long)c * q, qd = (long)q * d, cc = (long)c * c;
  const size_t dd = (size_t)d * d;
  const size_t wslice = (size_t)768 * 2304;
  const int cast_big = (int)(big / 8);
  (void)ws_size; (void)E0b;

  const float* x = U;
  for (int t = 0; t < T; ++t) {
    const float* Writ = Wri + (size_t)t * 4 * dd;
    const float* Wgit = Wgi + (size_t)t * 4 * dd;
    const float* Wrst = Wrs + (size_t)t * 4 * dd;
    const float* Wgst = Wgs + (size_t)t * 4 * dd;

    // -- prep: all 8 weight transposes of this stage in ONE launch --
    wprep<<<dim3(12, 48, 4), 256, 0, stream>>>(Writ, Wgit, Wrst, Wgst,
                                               Wu + t * dd, Wv + t * dd,
                                               W1 + t * dd, W2 + t * dd, Wt, WuT);
    if (t == 0) {
      cast_bf16<<<dim3((int)(smE / 8 / 256)), 256, 0, stream>>>(V, Vb16, (int)(smE / 8));
      transpV<<<dim3(12, 2, b), 256, 0, stream>>>(V, VTb);
      cast_bf16<<<dim3(cast_big / 256), 256, 0, stream>>>(x, XB0, cast_big);  // xb16 (U)
    }
    // t=1: XB0 already holds z bf16 from stage-0 step-13 dual write

    // 1+2 merged: Ctb = relu(x@Wu+bu) -> t1h  AND  Qtb = relu(V@Wv+bv) -> Qtbb
    mfma_relu_pair<<<dim3(12, 72), 512, 0, stream>>>(XB0, WuT, bu + t * d, t1h,
                                                     Vb16, WvT, bv + t * d, Qtbb);
    if (t == 0) {
      // 3. E0 = Ctb @ Qtb^T -> Ebuf (MFMA, N=96 clamped, TM=48)
      launch_mfma1(t1h, Qtbb, nullptr, nullptr, nullptr, Ebuf, nullptr,
                   c, q, d, cd, qd, 0, cq, 0, 0, b, 48, stream);
    } else {
      // 4a. EsT bf16 = row-softmax over c of (prev) E^T  [reads old Ebuf]
      transp_f32<<<dim3(2, 12, b), 256, 0, stream>>>(Ebuf, Esb, c, q, cq, cq);
      softmax_row_mask<<<dim3(q, b), 256, 0, stream>>>(Esb, Um, nullptr, EsTb, q, c);
      // 3+4c fused: E = Ctb@Qtb^T + gi * Btt_prev@Es  -> Ebuf (dual-product)
      mfma_dualE<<<dim3(2, 16, b), 256, 0, stream>>>(t1h, Qtbb, t3h2, EsTb,
                                                     gi + t, Ebuf,
                                                     c, q, d, c, cd, qd, cc, cq, cq);
    }
    // 5+6 fused: Mc2 = [qctx | x*qctx], qctx = rowsoftmax_Vm(E) @ V
    qctx_fused<<<dim3(12, 8, b), 512, 0, stream>>>(Ebuf, Vm, VTb, XB0, Mc2);
    // 7. h = SFU(x, qctx): seg0 streamed from XB0; writes h f32 + hb16 (XB1)
    sfu_mfma<<<dim3(12, 64), 512, 0, stream>>>(Mc2, XB0, Wt, Wt + wslice, x, h, XB1);
    // 8. H1,H2 dual-B (A = hb16 = XB1) -> bf16 H1b,H2b (overwrites Mc2 - dead)
    launch_mfma2(XB1, W1T, W2T, b1 + t * d, b2 + t * d, H1b, H2b,
                 b * c, d, d, 0, 0, 1, 1, stream);
    // 9/10. B0 and B carry
    if (t == 0) {
      launch_mfma1(H1b, H2b, nullptr, nullptr, nullptr, Bm, nullptr,
                   c, c, d, cd, cd, 0, cc, 0, 1, b, 96, stream);
    } else {
      // B1sT bf16 via 2-kernel fused col-softmax -> slotEb (t3h2 = Btt_prev
      // must survive until dual2 consumes it as A2)
      colsm_stats<<<dim3(12, 12, b), 256, 0, stream>>>(Bm, Um, SMst, SSst, c);
      colsm_emit<<<dim3(12, 12, b), 256, 0, stream>>>(Bm, Um, SMst, SSst, slotEb, c);
      // Bm = H1@H2^T + gs*(Btt_prev@B1s), zerodiag (fused dual-product GEMM)
      mfma_dual2<<<dim3(12, 8, b), 512, 0, stream>>>(H1b, H2b, t3h2, slotEb,
                                                     gs + t, Bm,
                                                     c, c, d, cd, cd, cc, cc, cc, 1);
    }
    // 11. Btt bf16 = softmax_row(mask_c(B)) -> t3h2 (feeds step 12 AND next
    //     stage's 4b-replacement / dualE A2)
    softmax_row_mask<<<dim3(c, b), 256, 0, stream>>>(Bm, Um, nullptr, t3h2, c, c);
    // 12. hT bf16 from XB1; hctx GEMM with Mc2-concat epilogue:
    //     Mc2 = [hctx | h*hctx] (x-source = XB1; overwrites H1b/H2b - dead)
    transp_bf16<<<dim3(12, 12, b), 256, 0, stream>>>(XB1, slotEb);
    launch_mfma1(t3h2, slotEb, nullptr, nullptr, nullptr, nullptr, nullptr,
                 c, d, c, cc, cd, 0, cd, 0, 0, b, 96, stream, XB1, Mc2);
    // 13. Z = SFU(h, hctx): seg0 streamed from XB1; dual-write z bf16 -> XB0
    float* zdst = (t == T - 1) ? out : xbuf;
    unsigned short* zb16 = (t == T - 1) ? nullptr : XB0;
    sfu_mfma<<<dim3(12, 64), 512, 0, stream>>>(Mc2, XB1, Wt + 2 * wslice, Wt + 3 * wslice,
                                               h, zdst, zb16);

    x = xbuf;
  }
}

// Round 16
// 619.885 us; speedup vs baseline: 1.0211x; 1.0211x over previous
//
#include <hip/hip_runtime.h>
#include <math.h>

#define NEGV -1e9f

typedef short bf16x8 __attribute__((ext_vector_type(8)));
typedef float f32x4 __attribute__((ext_vector_type(4)));
typedef unsigned short ushort8v __attribute__((ext_vector_type(8)));

static __device__ __forceinline__ unsigned short f2bf(float f) {
  unsigned int u = __float_as_uint(f);
  unsigned int r = (u + 0x7fffu + ((u >> 16) & 1u)) >> 16;
  return (unsigned short)r;
}
static __device__ __forceinline__ float bf2f(unsigned short u) {
  return __uint_as_float((unsigned int)u << 16);
}

// bijective XCD-chunking swizzle (m204 form)
static __device__ __forceinline__ int xcd_swz(int lin, int nwg) {
  int q = nwg >> 3, r = nwg & 7;
  int x = lin & 7, i = lin >> 3;
  return (x < r) ? x * (q + 1) + i : r * (q + 1) + (x - r) * q + i;
}

// ---------------------------------------------------------------------------
// reductions
// ---------------------------------------------------------------------------
__device__ __forceinline__ float wred_max(float v) {
  #pragma unroll
  for (int o = 32; o > 0; o >>= 1) v = fmaxf(v, __shfl_down(v, o, 64));
  return v;
}
__device__ __forceinline__ float wred_sum(float v) {
  #pragma unroll
  for (int o = 32; o > 0; o >>= 1) v += __shfl_down(v, o, 64);
  return v;
}

// ---------------------------------------------------------------------------
// masked softmax over LAST dim (3-pass). X: (batch,R,Cn). Used for 4a only.
// ---------------------------------------------------------------------------
__global__ __launch_bounds__(256)
void softmax_row_mask(const float* __restrict__ X, const int* __restrict__ mask,
                      float* __restrict__ Y, unsigned short* __restrict__ Ybf,
                      int R, int Cn)
{
  int bz = blockIdx.y, r = blockIdx.x, tid = threadIdx.x;
  const float* xr = X + ((size_t)bz * R + r) * Cn;
  const int*   mr = mask + (size_t)bz * Cn;
  float*       yr = Y ? (Y + ((size_t)bz * R + r) * Cn) : nullptr;
  unsigned short* yb = Ybf ? (Ybf + ((size_t)bz * R + r) * Cn) : nullptr;
  __shared__ float sred[4];

  float mx = -INFINITY;
  for (int i = tid; i < Cn; i += 256) {
    float v = (mr[i] != 0) ? xr[i] : NEGV;
    mx = fmaxf(mx, v);
  }
  float wm = wred_max(mx);
  if ((tid & 63) == 0) sred[tid >> 6] = wm;
  __syncthreads();
  mx = fmaxf(fmaxf(sred[0], sred[1]), fmaxf(sred[2], sred[3]));
  __syncthreads();

  float s = 0.f;
  for (int i = tid; i < Cn; i += 256) {
    float v = (mr[i] != 0) ? xr[i] : NEGV;
    s += expf(v - mx);
  }
  float wsv = wred_sum(s);
  if ((tid & 63) == 0) sred[tid >> 6] = wsv;
  __syncthreads();
  s = sred[0] + sred[1] + sred[2] + sred[3];
  float inv = 1.0f / s;

  for (int i = tid; i < Cn; i += 256) {
    float v = (mr[i] != 0) ? xr[i] : NEGV;
    float o = expf(v - mx) * inv;
    if (yr) yr[i] = o;
    if (yb) yb[i] = f2bf(o);
  }
}

// ---------------------------------------------------------------------------
// batched f32 tiled transpose: X (batch, R, C) -> Y (batch, C, R) [4a]
// ---------------------------------------------------------------------------
__global__ __launch_bounds__(256)
void transp_f32(const float* __restrict__ X, float* __restrict__ Y,
                int R, int C, long sX, long sY)
{
  int bz = blockIdx.z;
  X += (size_t)bz * sX;
  Y += (size_t)bz * sY;
  __shared__ float T[64][65];
  int c0 = blockIdx.x * 64, r0 = blockIdx.y * 64;
  int t = threadIdx.x;
  int tr = t >> 4, tc4 = (t & 15) * 4;
  #pragma unroll
  for (int rr = 0; rr < 4; ++rr) {
    int r = tr + rr * 16;
    float4 v = make_float4(0.f, 0.f, 0.f, 0.f);
    if (c0 + tc4 < C)
      v = *reinterpret_cast<const float4*>(X + (size_t)(r0 + r) * C + c0 + tc4);
    T[r][tc4 + 0] = v.x; T[r][tc4 + 1] = v.y;
    T[r][tc4 + 2] = v.z; T[r][tc4 + 3] = v.w;
  }
  __syncthreads();
  #pragma unroll
  for (int rr = 0; rr < 4; ++rr) {
    int cc = tr + rr * 16;
    int gc = c0 + cc;
    if (gc < C) {
      float4 o = make_float4(T[tc4 + 0][cc], T[tc4 + 1][cc], T[tc4 + 2][cc], T[tc4 + 3][cc]);
      *reinterpret_cast<float4*>(Y + (size_t)gc * R + r0 + tc4) = o;
    }
  }
}

// ---------------------------------------------------------------------------
// transpose V: (batch, 96, 768) f32 -> VTb (batch, 768, 96) bf16
// ---------------------------------------------------------------------------
__global__ __launch_bounds__(256)
void transpV(const float* __restrict__ V, unsigned short* __restrict__ VT)
{
  int bz = blockIdx.z;
  const float* Vb = V + (size_t)bz * 96 * 768;
  unsigned short* Yb = VT + (size_t)bz * 768 * 96;
  __shared__ float T[64][65];
  int c0 = blockIdx.x * 64, r0 = blockIdx.y * 64;
  int t = threadIdx.x;
  int tr = t >> 4, tc4 = (t & 15) * 4;
  #pragma unroll
  for (int rr = 0; rr < 4; ++rr) {
    int r = tr + rr * 16;
    int gr = r0 + r;
    float4 v = make_float4(0.f, 0.f, 0.f, 0.f);
    if (gr < 96)
      v = *reinterpret_cast<const float4*>(Vb + (size_t)gr * 768 + c0 + tc4);
    T[r][tc4 + 0] = v.x; T[r][tc4 + 1] = v.y;
    T[r][tc4 + 2] = v.z; T[r][tc4 + 3] = v.w;
  }
  __syncthreads();
  #pragma unroll
  for (int rr = 0; rr < 4; ++rr) {
    int cc = tr + rr * 16;
    int gc = c0 + cc;
    #pragma unroll
    for (int e = 0; e < 4; ++e) {
      int gr = r0 + tc4 + e;
      if (gr < 96) Yb[(size_t)gc * 96 + gr] = f2bf(T[tc4 + e][cc]);
    }
  }
}

// ---------------------------------------------------------------------------
// flat f32 -> bf16 cast. n8 = elems/8.
// ---------------------------------------------------------------------------
__global__ __launch_bounds__(256)
void cast_bf16(const float* __restrict__ X, unsigned short* __restrict__ Y, int n8)
{
  int idx = blockIdx.x * 256 + threadIdx.x;
  if (idx >= n8) return;
  float4 a0 = *reinterpret_cast<const float4*>(X + (size_t)idx * 8);
  float4 a1 = *reinterpret_cast<const float4*>(X + (size_t)idx * 8 + 4);
  ushort8v o;
  o[0] = f2bf(a0.x); o[1] = f2bf(a0.y); o[2] = f2bf(a0.z); o[3] = f2bf(a0.w);
  o[4] = f2bf(a1.x); o[5] = f2bf(a1.y); o[6] = f2bf(a1.z); o[7] = f2bf(a1.w);
  *reinterpret_cast<ushort8v*>(Y + (size_t)idx * 8) = o;
}

// ===========================================================================
// R16 fused independent-dispatch kernels (pure overlap, math bit-identical):
//
// fused_tail (after Bm finalized):
//   blocks [0,6144)      : softmax_row over Bm rows -> Btt bf16 (t3h2)
//   blocks [6144,7296)   : bf16 transpose XB1 -> hT (slotEb)
//   blocks [7296,8448)   : colsm_stats over Bm (only launched at t<T-1)
//
// fused_prep (stage start):
//   blocks [0,2304)      : wprep (8 weight transposes)
//   blocks [2304,3456)   : colsm_emit -> B1sT (slotEb)  (only at t>0)
// ===========================================================================
__global__ __launch_bounds__(256)
void fused_tail(const float* __restrict__ Bm, const int* __restrict__ Um,
                unsigned short* __restrict__ Btt,
                const unsigned short* __restrict__ Hb, unsigned short* __restrict__ HT,
                float* __restrict__ SM, float* __restrict__ SS)
{
  int bid = blockIdx.x;
  int tid = threadIdx.x;

  if (bid < 6144) {
    // ---- masked row-softmax of Bm (R=768, Cn=768) -> bf16 ----
    int bz = bid / 768, r = bid - bz * 768;
    const float* xr = Bm + ((size_t)bz * 768 + r) * 768;
    const int*   mr = Um + (size_t)bz * 768;
    unsigned short* yb = Btt + ((size_t)bz * 768 + r) * 768;
    __shared__ float sred[4];

    float mx = -INFINITY;
    for (int i = tid; i < 768; i += 256) {
      float v = (mr[i] != 0) ? xr[i] : NEGV;
      mx = fmaxf(mx, v);
    }
    float wm = wred_max(mx);
    if ((tid & 63) == 0) sred[tid >> 6] = wm;
    __syncthreads();
    mx = fmaxf(fmaxf(sred[0], sred[1]), fmaxf(sred[2], sred[3]));
    __syncthreads();
    float s = 0.f;
    for (int i = tid; i < 768; i += 256) {
      float v = (mr[i] != 0) ? xr[i] : NEGV;
      s += expf(v - mx);
    }
    float wsv = wred_sum(s);
    if ((tid & 63) == 0) sred[tid >> 6] = wsv;
    __syncthreads();
    s = sred[0] + sred[1] + sred[2] + sred[3];
    float inv = 1.0f / s;
    for (int i = tid; i < 768; i += 256) {
      float v = (mr[i] != 0) ? xr[i] : NEGV;
      yb[i] = f2bf(expf(v - mx) * inv);
    }
  } else if (bid < 7296) {
    // ---- bf16 768x768 transpose: Hb -> HT ----
    int idx = bid - 6144;
    int bx = idx % 12; idx /= 12;
    int by = idx % 12; int bz = idx / 12;
    const unsigned short* X = Hb + (size_t)bz * 589824;
    unsigned short* Y = HT + (size_t)bz * 589824;
    __shared__ unsigned short T[64][65];
    int c0 = bx * 64, r0 = by * 64;
    int tr = tid >> 4, tc4 = (tid & 15) * 4;
    #pragma unroll
    for (int rr = 0; rr < 4; ++rr) {
      int r = tr + rr * 16;
      ushort4 v = *reinterpret_cast<const ushort4*>(X + (size_t)(r0 + r) * 768 + c0 + tc4);
      T[r][tc4 + 0] = v.x; T[r][tc4 + 1] = v.y;
      T[r][tc4 + 2] = v.z; T[r][tc4 + 3] = v.w;
    }
    __syncthreads();
    #pragma unroll
    for (int rr = 0; rr < 4; ++rr) {
      int cc = tr + rr * 16;
      ushort4 o;
      o.x = T[tc4 + 0][cc]; o.y = T[tc4 + 1][cc];
      o.z = T[tc4 + 2][cc]; o.w = T[tc4 + 3][cc];
      *reinterpret_cast<ushort4*>(Y + (size_t)(c0 + cc) * 768 + r0 + tc4) = o;
    }
  } else {
    // ---- colsm_stats over Bm (n=768), mask on ROW index ----
    int idx = bid - 7296;
    int bx = idx % 12; idx /= 12;
    int by = idx % 12; int bz = idx / 12;
    const float* Xb = Bm + (size_t)bz * 589824;
    const int*   mr = Um + (size_t)bz * 768;
    __shared__ float T[64][65];
    __shared__ float rm[4][64], rs[4][64];
    int j0 = bx * 64, i0 = by * 64;
    int tr = tid >> 4, tc4 = (tid & 15) * 4;
    int jj = tid & 63, qq = tid >> 6;

    #pragma unroll
    for (int r = 0; r < 4; ++r) {
      int i = tr + r * 16;
      float4 v = *reinterpret_cast<const float4*>(Xb + (size_t)(i0 + i) * 768 + j0 + tc4);
      int mk = mr[i0 + i];
      T[i][tc4 + 0] = mk ? v.x : NEGV;
      T[i][tc4 + 1] = mk ? v.y : NEGV;
      T[i][tc4 + 2] = mk ? v.z : NEGV;
      T[i][tc4 + 3] = mk ? v.w : NEGV;
    }
    __syncthreads();
    float m = -INFINITY, s = 0.f;
    #pragma unroll
    for (int r = 0; r < 16; ++r) {
      float v = T[qq * 16 + r][jj];
      float nm = fmaxf(m, v);
      s = s * expf(m - nm) + expf(v - nm);
      m = nm;
    }
    rm[qq][jj] = m; rs[qq][jj] = s;
    __syncthreads();
    if (tid < 64) {
      float m0 = rm[0][tid], m1 = rm[1][tid], m2 = rm[2][tid], m3 = rm[3][tid];
      float fm = fmaxf(fmaxf(m0, m1), fmaxf(m2, m3));
      float fs = rs[0][tid] * expf(m0 - fm) + rs[1][tid] * expf(m1 - fm)
               + rs[2][tid] * expf(m2 - fm) + rs[3][tid] * expf(m3 - fm);
      size_t base = (((size_t)bz * 12 + bx) * 12 + by) * 64 + tid;
      SM[base] = fm; SS[base] = fs;
    }
  }
}

__global__ __launch_bounds__(256)
void fused_prep(const float* __restrict__ S0, const float* __restrict__ S1,
                const float* __restrict__ S2, const float* __restrict__ S3,
                const float* __restrict__ W0, const float* __restrict__ W1a,
                const float* __restrict__ W2a, const float* __restrict__ W3a,
                unsigned short* __restrict__ Wt, unsigned short* __restrict__ WuT,
                const float* __restrict__ Bm, const int* __restrict__ Um,
                const float* __restrict__ SM, const float* __restrict__ SS,
                unsigned short* __restrict__ B1sT)
{
  int bid = blockIdx.x;
  int tid = threadIdx.x;
  int tr = tid >> 4, tc4 = (tid & 15) * 4;

  if (bid < 2304) {
    // ---- wprep: z = bid/576, by = (bid%576)/12, bx = bid%12 ----
    int z = bid / 576;
    int rem = bid - z * 576;
    int by = rem / 12, bx = rem - by * 12;
    __shared__ float T[64][65];
    int n0 = bx * 64;

    if (by < 36) {
      const float* W = (z == 0) ? S0 : (z == 1) ? S1 : (z == 2) ? S2 : S3;
      unsigned short* Y = Wt + (size_t)z * 768 * 2304;
      int k0 = by * 64;
      #pragma unroll
      for (int r = 0; r < 4; ++r) {
        int k = tr + r * 16;
        int gk = k0 + k;
        float4 v = *reinterpret_cast<const float4*>(W + (size_t)gk * 768 + n0 + tc4);
        if (gk < 768) {
          float4 u = *reinterpret_cast<const float4*>(W + (size_t)(gk + 2304) * 768 + n0 + tc4);
          v.x += u.x; v.y += u.y; v.z += u.z; v.w += u.w;
        } else if (gk < 1536) {
          float4 u = *reinterpret_cast<const float4*>(W + (size_t)(gk + 1536) * 768 + n0 + tc4);
          v.x -= u.x; v.y -= u.y; v.z -= u.z; v.w -= u.w;
        }
        T[k][tc4 + 0] = v.x; T[k][tc4 + 1] = v.y; T[k][tc4 + 2] = v.z; T[k][tc4 + 3] = v.w;
      }
      __syncthreads();
      #pragma unroll
      for (int r = 0; r < 4; ++r) {
        int n = tr + r * 16;
        ushort4 o;
        o.x = f2bf(T[tc4 + 0][n]); o.y = f2bf(T[tc4 + 1][n]);
        o.z = f2bf(T[tc4 + 2][n]); o.w = f2bf(T[tc4 + 3][n]);
        *reinterpret_cast<ushort4*>(Y + (size_t)(n0 + n) * 2304 + k0 + tc4) = o;
      }
    } else {
      const float* W = (z == 0) ? W0 : (z == 1) ? W1a : (z == 2) ? W2a : W3a;
      unsigned short* Y = WuT + (size_t)z * 768 * 768;
      int k0 = (by - 36) * 64;
      #pragma unroll
      for (int r = 0; r < 4; ++r) {
        int k = tr + r * 16;
        float4 v = *reinterpret_cast<const float4*>(W + (size_t)(k0 + k) * 768 + n0 + tc4);
        T[k][tc4 + 0] = v.x; T[k][tc4 + 1] = v.y; T[k][tc4 + 2] = v.z; T[k][tc4 + 3] = v.w;
      }
      __syncthreads();
      #pragma unroll
      for (int r = 0; r < 4; ++r) {
        int n = tr + r * 16;
        ushort4 o;
        o.x = f2bf(T[tc4 + 0][n]); o.y = f2bf(T[tc4 + 1][n]);
        o.z = f2bf(T[tc4 + 2][n]); o.w = f2bf(T[tc4 + 3][n]);
        *reinterpret_cast<ushort4*>(Y + (size_t)(n0 + n) * 768 + k0 + tc4) = o;
      }
    }
  } else {
    // ---- colsm_emit over Bm (n=768): Y[b][j][i] transposed bf16 -> B1sT ----
    int idx = bid - 2304;
    int bx = idx % 12; idx /= 12;
    int by = idx % 12; int bz = idx / 12;
    const float* Xb = Bm + (size_t)bz * 589824;
    const int*   mr = Um + (size_t)bz * 768;
    unsigned short* Yb = B1sT + (size_t)bz * 589824;
    __shared__ float T2[64][65];
    __shared__ float sm[64], sinv[64];
    int j0 = bx * 64, i0 = by * 64;

    if (tid < 64) {
      size_t base = (((size_t)bz * 12 + bx) * 12) * 64 + tid;
      float fm = -INFINITY;
      for (int it = 0; it < 12; ++it) fm = fmaxf(fm, SM[base + (size_t)it * 64]);
      float fs = 0.f;
      for (int it = 0; it < 12; ++it)
        fs += SS[base + (size_t)it * 64] * expf(SM[base + (size_t)it * 64] - fm);
      sm[tid] = fm; sinv[tid] = 1.0f / fs;
    }
    #pragma unroll
    for (int r = 0; r < 4; ++r) {
      int i = tr + r * 16;
      float4 v = *reinterpret_cast<const float4*>(Xb + (size_t)(i0 + i) * 768 + j0 + tc4);
      int mk = mr[i0 + i];
      T2[i][tc4 + 0] = mk ? v.x : NEGV;
      T2[i][tc4 + 1] = mk ? v.y : NEGV;
      T2[i][tc4 + 2] = mk ? v.z : NEGV;
      T2[i][tc4 + 3] = mk ? v.w : NEGV;
    }
    __syncthreads();
    #pragma unroll
    for (int r = 0; r < 4; ++r) {
      int jr = tr + r * 16;
      float fm = sm[jr], inv = sinv[jr];
      ushort4 o;
      o.x = f2bf(expf(T2[tc4 + 0][jr] - fm) * inv);
      o.y = f2bf(expf(T2[tc4 + 1][jr] - fm) * inv);
      o.z = f2bf(expf(T2[tc4 + 2][jr] - fm) * inv);
      o.w = f2bf(expf(T2[tc4 + 3][jr] - fm) * inv);
      *reinterpret_cast<ushort4*>(Yb + (size_t)(j0 + jr) * 768 + i0 + tc4) = o;
    }
  }
}

// ===========================================================================
// Swizzled LDS layout (verified r9, conflicts -> 0):
//   staging source granule pre-swizzled (gsrc = (l&3)^((l>>3)&3)), LDS dest
//   linear; read offset prm = ((l>>4)^((l>>1)&3))*8 ushorts.
//   Direct-write mapping (row r, granule G):
//     ushort idx = (r>>4)*512 + ((r&15)*4 + (G ^ ((r>>1)&3)))*8
// ===========================================================================

template<int NB, int WAVES>
__global__ __launch_bounds__(64 * WAVES)
void mfma_gemm(const unsigned short* __restrict__ A,
               const unsigned short* __restrict__ Bt0,
               const unsigned short* __restrict__ Bt1,
               const float* __restrict__ bias0, const float* __restrict__ bias1,
               const float* __restrict__ alphap, const float* __restrict__ C0,
               float* __restrict__ F0, float* __restrict__ F1,
               unsigned short* __restrict__ O0, unsigned short* __restrict__ O1,
               int M, int N, int K,
               long sA, long sB, long sC0, long sC,
               int relu, int zerodiag,
               const unsigned short* __restrict__ Xc, unsigned short* __restrict__ McO)
{
  const int RG = WAVES / 4;
  const int TM = RG * 48;
  __shared__ unsigned short As[2][TM * 32];
  __shared__ unsigned short Bs0[2][2048];
  __shared__ unsigned short Bs1[2][NB == 2 ? 2048 : 16];

  int nx = gridDim.x, ny = gridDim.y;
  int nwg = nx * ny * gridDim.z;
  int lin = blockIdx.x + nx * (blockIdx.y + ny * blockIdx.z);
  int sw = xcd_swz(lin, nwg);
  int bxi = sw % nx; int rest = sw / nx;
  int byi = rest % ny; int bz = rest / ny;

  A   += (size_t)bz * sA;
  Bt0 += (size_t)bz * sB;
  if (NB == 2) Bt1 += (size_t)bz * sB;
  const float* C0b = C0 ? (C0 + (size_t)bz * sC0) : nullptr;

  int tid = threadIdx.x;
  int w = tid >> 6, l = tid & 63;
  int m0 = byi * TM, n0 = bxi * 64;
  int wr = w >> 2, wc = w & 3;

  int g8 = (((l & 3) ^ ((l >> 3) & 3))) * 8;
  int rowA = w * 16 + (l >> 2); if (rowA > TM - 1) rowA = TM - 1;
  int rB = n0 + (w & 3) * 16 + (l >> 2); if (rB > N - 1) rB = N - 1;
  const unsigned short* srcA  = A + (size_t)(m0 + rowA) * K + g8;
  const unsigned short* srcB0 = Bt0 + (size_t)rB * K + g8;
  const unsigned short* srcB1 = (NB == 2) ? Bt1 + (size_t)rB * K + g8 : nullptr;

#define GG_STAGE(kt, bi) do { int kk0 = (kt) * 32;                                                                        \
    if (w < TM / 16)                                                                                                      \
      __builtin_amdgcn_global_load_lds((const unsigned int*)(srcA + kk0),  (unsigned int*)&As[bi][0]  + w * 256, 16, 0, 0); \
    if (w < 4)                                                                                                            \
      __builtin_amdgcn_global_load_lds((const unsigned int*)(srcB0 + kk0), (unsigned int*)&Bs0[bi][0] + w * 256, 16, 0, 0); \
    if (NB == 2 && w >= 4)                                                                                                \
      __builtin_amdgcn_global_load_lds((const unsigned int*)(srcB1 + kk0), (unsigned int*)&Bs1[bi][0] + (w - 4) * 256, 16, 0, 0); \
  } while (0)

  f32x4 a0[3] = {};
  f32x4 a1v[3] = {};

  const int NT = K / 32;
  int prm = ((l >> 4) ^ ((l >> 1) & 3)) * 8;
  GG_STAGE(0, 0);
  __syncthreads();
  int cur = 0;
  for (int kt = 0; kt < NT; ++kt) {
    if (kt + 1 < NT) GG_STAGE(kt + 1, cur ^ 1);

    bf16x8 af[3];
    #pragma unroll
    for (int i = 0; i < 3; ++i) {
      int off = (wr * 48 + i * 16 + (l & 15)) * 32 + prm;
      af[i] = *reinterpret_cast<const bf16x8*>(&As[cur][off]);
    }
    int offB = (wc * 16 + (l & 15)) * 32 + prm;
    bf16x8 b0 = *reinterpret_cast<const bf16x8*>(&Bs0[cur][offB]);
    #pragma unroll
    for (int i = 0; i < 3; ++i)
      a0[i] = __builtin_amdgcn_mfma_f32_16x16x32_bf16(af[i], b0, a0[i], 0, 0, 0);
    if (NB == 2) {
      bf16x8 b1 = *reinterpret_cast<const bf16x8*>(&Bs1[cur][offB]);
      #pragma unroll
      for (int i = 0; i < 3; ++i)
        a1v[i] = __builtin_amdgcn_mfma_f32_16x16x32_bf16(af[i], b1, a1v[i], 0, 0, 0);
    }
    __syncthreads();
    cur ^= 1;
  }
#undef GG_STAGE

  float alpha = alphap ? alphap[0] : 1.0f;
  float* F0b = F0 ? F0 + (size_t)bz * sC : nullptr;
  float* F1b = F1 ? F1 + (size_t)bz * sC : nullptr;
  unsigned short* O0b = O0 ? O0 + (size_t)bz * sC : nullptr;
  unsigned short* O1b = O1 ? O1 + (size_t)bz * sC : nullptr;
  const unsigned short* Xcb = Xc ? Xc + (size_t)bz * 589824 : nullptr;
  unsigned short* Mcb = McO ? McO + (size_t)bz * 1179648 : nullptr;   // 768*1536

  #pragma unroll
  for (int i = 0; i < 3; ++i) {
    #pragma unroll
    for (int qq = 0; qq < 4; ++qq) {
      int gm = m0 + wr * 48 + i * 16 + (l >> 4) * 4 + qq;
      int gn = n0 + wc * 16 + (l & 15);
      if (gn >= N) continue;
      size_t oidx = (size_t)gm * N + gn;
      float v = alpha * a0[i][qq];
      if (bias0) v += bias0[gn];
      if (relu) v = fmaxf(v, 0.f);
      if (C0b) v += C0b[oidx];
      if (zerodiag && gm == gn) v = 0.f;
      if (Mcb) {
        float xv = bf2f(Xcb[(size_t)gm * 768 + gn]);
        size_t mrow = (size_t)gm * 1536 + gn;
        Mcb[mrow]        = f2bf(v);
        Mcb[mrow + 768]  = f2bf(xv * v);
      }
      if (F0b) F0b[oidx] = v;
      if (O0b) O0b[oidx] = f2bf(v);
      if (NB == 2) {
        float v1 = alpha * a1v[i][qq];
        if (bias1) v1 += bias1[gn];
        if (relu) v1 = fmaxf(v1, 0.f);
        if (F1b) F1b[oidx] = v1;
        if (O1b) O1b[oidx] = f2bf(v1);
      }
    }
  }
}

// ---------------------------------------------------------------------------
// Merged step-1 + step-2 relu-GEMM pair (both K=768, N=768, TM=96, bf16 out).
// grid (12, 72): byi<64 -> GEMM1 (M=6144), byi>=64 -> GEMM2 (M=768).
// ---------------------------------------------------------------------------
__global__ __launch_bounds__(512)
void mfma_relu_pair(const unsigned short* __restrict__ A1g,
                    const unsigned short* __restrict__ B1g,
                    const float* __restrict__ bias1g, unsigned short* __restrict__ O1g,
                    const unsigned short* __restrict__ A2g,
                    const unsigned short* __restrict__ B2g,
                    const float* __restrict__ bias2g, unsigned short* __restrict__ O2g)
{
  const int K = 768, N = 768, NT = 24;
  __shared__ unsigned short As[2][3072];
  __shared__ unsigned short Bs0[2][2048];

  int nx = gridDim.x, ny = gridDim.y;
  int nwg = nx * ny;
  int lin = blockIdx.x + nx * blockIdx.y;
  int sw = xcd_swz(lin, nwg);
  int bxi = sw % nx; int byi = sw / nx;

  const unsigned short* A; const unsigned short* Bt;
  const float* bias; unsigned short* O;
  int m0;
  if (byi < 64) { A = A1g; Bt = B1g; bias = bias1g; O = O1g; m0 = byi * 96; }
  else          { A = A2g; Bt = B2g; bias = bias2g; O = O2g; m0 = (byi - 64) * 96; }

  int tid = threadIdx.x;
  int w = tid >> 6, l = tid & 63;
  int n0 = bxi * 64;
  int wr = w >> 2, wc = w & 3;

  int g8 = (((l & 3) ^ ((l >> 3) & 3))) * 8;
  int rowA = w * 16 + (l >> 2); if (rowA > 95) rowA = 95;  // w<6 only
  int rB = n0 + (w & 3) * 16 + (l >> 2);
  const unsigned short* srcA  = A + (size_t)(m0 + rowA) * K + g8;
  const unsigned short* srcB0 = Bt + (size_t)rB * K + g8;

#define RP_STAGE(kt, bi) do { int kk0 = (kt) * 32;                                                                        \
    if (w < 6)                                                                                                            \
      __builtin_amdgcn_global_load_lds((const unsigned int*)(srcA + kk0),  (unsigned int*)&As[bi][0]  + w * 256, 16, 0, 0); \
    if (w < 4)                                                                                                            \
      __builtin_amdgcn_global_load_lds((const unsigned int*)(srcB0 + kk0), (unsigned int*)&Bs0[bi][0] + w * 256, 16, 0, 0); \
  } while (0)

  f32x4 a0[3] = {};
  int prm = ((l >> 4) ^ ((l >> 1) & 3)) * 8;
  RP_STAGE(0, 0);
  __syncthreads();
  int cur = 0;
  for (int kt = 0; kt < NT; ++kt) {
    if (kt + 1 < NT) RP_STAGE(kt + 1, cur ^ 1);

    bf16x8 af[3];
    #pragma unroll
    for (int i = 0; i < 3; ++i) {
      int off = (wr * 48 + i * 16 + (l & 15)) * 32 + prm;
      af[i] = *reinterpret_cast<const bf16x8*>(&As[cur][off]);
    }
    int offB = (wc * 16 + (l & 15)) * 32 + prm;
    bf16x8 b0 = *reinterpret_cast<const bf16x8*>(&Bs0[cur][offB]);
    #pragma unroll
    for (int i = 0; i < 3; ++i)
      a0[i] = __builtin_amdgcn_mfma_f32_16x16x32_bf16(af[i], b0, a0[i], 0, 0, 0);
    __syncthreads();
    cur ^= 1;
  }
#undef RP_STAGE

  #pragma unroll
  for (int i = 0; i < 3; ++i) {
    #pragma unroll
    for (int qq = 0; qq < 4; ++qq) {
      int gm = m0 + wr * 48 + i * 16 + (l >> 4) * 4 + qq;
      int gn = n0 + wc * 16 + (l & 15);
      float v = a0[i][qq] + bias[gn];
      v = fmaxf(v, 0.f);
      O[(size_t)gm * N + gn] = f2bf(v);
    }
  }
}

// ---------------------------------------------------------------------------
// Fused step-5 + step-6: qctx = rowsoftmax_mask(E) @ V, Mc2-concat epilogue
// (writes [f | x*f], stride 1536; x read from Xb16). grid (12,8,b), 512 thr.
// ---------------------------------------------------------------------------
__global__ __launch_bounds__(512)
void qctx_fused(const float* __restrict__ E, const int* __restrict__ Vm,
                const unsigned short* __restrict__ VTb,
                const unsigned short* __restrict__ Xb16, unsigned short* __restrict__ Mc)
{
  __shared__ unsigned short As3[3][3072];
  __shared__ unsigned short Bs3[3][2048];
  __shared__ int mk[96];

  int nx = gridDim.x, ny = gridDim.y;
  int nwg = nx * ny * gridDim.z;
  int lin = blockIdx.x + nx * (blockIdx.y + ny * blockIdx.z);
  int sw = xcd_swz(lin, nwg);
  int bxi = sw % nx; int rest = sw / nx;
  int byi = rest % ny; int bz = rest / ny;

  int tid = threadIdx.x;
  int w = tid >> 6, l = tid & 63;
  int m0 = byi * 96, n0 = bxi * 64;

  int g8 = (((l & 3) ^ ((l >> 3) & 3))) * 8;
  if (w < 4) {
    int rB = n0 + w * 16 + (l >> 2);
    const unsigned short* srcB = VTb + ((size_t)bz * 768 + rB) * 96 + g8;
    #pragma unroll
    for (int kt = 0; kt < 3; ++kt)
      __builtin_amdgcn_global_load_lds((const unsigned int*)(srcB + kt * 32),
                                       (unsigned int*)&Bs3[kt][0] + w * 256, 16, 0, 0);
  }
  if (tid < 96) mk[tid] = Vm[bz * 96 + tid];
  __syncthreads();

  if (tid < 384) {
    int r = tid >> 2, j4 = tid & 3;
    const float* er = E + ((size_t)bz * 768 + m0 + r) * 96 + j4 * 24;
    float va[24];
    #pragma unroll
    for (int u = 0; u < 6; ++u) {
      float4 v = *reinterpret_cast<const float4*>(er + u * 4);
      int kb = j4 * 24 + u * 4;
      va[u * 4 + 0] = mk[kb + 0] ? v.x : NEGV;
      va[u * 4 + 1] = mk[kb + 1] ? v.y : NEGV;
      va[u * 4 + 2] = mk[kb + 2] ? v.z : NEGV;
      va[u * 4 + 3] = mk[kb + 3] ? v.w : NEGV;
    }
    float mx = -INFINITY;
    #pragma unroll
    for (int u = 0; u < 24; ++u) mx = fmaxf(mx, va[u]);
    mx = fmaxf(mx, __shfl_xor(mx, 1, 64));
    mx = fmaxf(mx, __shfl_xor(mx, 2, 64));
    float s = 0.f;
    #pragma unroll
    for (int u = 0; u < 24; ++u) { va[u] = expf(va[u] - mx); s += va[u]; }
    s += __shfl_xor(s, 1, 64);
    s += __shfl_xor(s, 2, 64);
    float inv = 1.0f / s;
    #pragma unroll
    for (int g = 0; g < 3; ++g) {
      int gG = j4 * 3 + g;
      int kt = gG >> 2, Gin = gG & 3;
      ushort8v o;
      #pragma unroll
      for (int e = 0; e < 8; ++e) o[e] = f2bf(va[g * 8 + e] * inv);
      int idx = (r >> 4) * 512 + ((r & 15) * 4 + (Gin ^ ((r >> 1) & 3))) * 8;
      *reinterpret_cast<ushort8v*>(&As3[kt][idx]) = o;
    }
  }
  __syncthreads();

  int wr = w >> 2, wc = w & 3;
  int prm = ((l >> 4) ^ ((l >> 1) & 3)) * 8;
  f32x4 acc[3] = {};
  #pragma unroll
  for (int kt = 0; kt < 3; ++kt) {
    bf16x8 af[3];
    #pragma unroll
    for (int i = 0; i < 3; ++i) {
      int off = (wr * 48 + i * 16 + (l & 15)) * 32 + prm;
      af[i] = *reinterpret_cast<const bf16x8*>(&As3[kt][off]);
    }
    int offB = (wc * 16 + (l & 15)) * 32 + prm;
    bf16x8 b0 = *reinterpret_cast<const bf16x8*>(&Bs3[kt][offB]);
    #pragma unroll
    for (int i = 0; i < 3; ++i)
      acc[i] = __builtin_amdgcn_mfma_f32_16x16x32_bf16(af[i], b0, acc[i], 0, 0, 0);
  }

  const unsigned short* Xb = Xb16 + (size_t)bz * 589824;
  unsigned short* Mcb = Mc + (size_t)bz * 1179648;
  #pragma unroll
  for (int i = 0; i < 3; ++i) {
    #pragma unroll
    for (int qq = 0; qq < 4; ++qq) {
      int gm = m0 + wr * 48 + i * 16 + (l >> 4) * 4 + qq;
      int gn = n0 + wc * 16 + (l & 15);
      float v = acc[i][qq];
      float xv = bf2f(Xb[(size_t)gm * 768 + gn]);
      size_t mrow = (size_t)gm * 1536 + gn;
      Mcb[mrow]        = f2bf(v);
      Mcb[mrow + 768]  = f2bf(xv * v);
    }
  }
}

// ---------------------------------------------------------------------------
// Fused dual-PRODUCT GEMM (8-wave): F0 = A1@B1t^T + alpha*(A2@B2t^T).
// ---------------------------------------------------------------------------
__global__ __launch_bounds__(512)
void mfma_dual2(const unsigned short* __restrict__ A1,
                const unsigned short* __restrict__ B1t,
                const unsigned short* __restrict__ A2,
                const unsigned short* __restrict__ B2t,
                const float* __restrict__ alphap, float* __restrict__ F0,
                int M, int N, int K,
                long sA1, long sB1, long sA2, long sB2, long sC,
                int zerodiag)
{
  __shared__ unsigned short As1[2][3072], Bs1[2][2048];
  __shared__ unsigned short As2[2][3072], Bs2[2][2048];

  int nx = gridDim.x, ny = gridDim.y;
  int nwg = nx * ny * gridDim.z;
  int lin = blockIdx.x + nx * (blockIdx.y + ny * blockIdx.z);
  int sw = xcd_swz(lin, nwg);
  int bxi = sw % nx; int rest = sw / nx;
  int byi = rest % ny; int bz = rest / ny;

  A1  += (size_t)bz * sA1;
  B1t += (size_t)bz * sB1;
  A2  += (size_t)bz * sA2;
  B2t += (size_t)bz * sB2;

  int tid = threadIdx.x;
  int w = tid >> 6, l = tid & 63;
  int m0 = byi * 96, n0 = bxi * 64;
  int wr = w >> 2, wc = w & 3;

  int g8 = (((l & 3) ^ ((l >> 3) & 3))) * 8;
  int rowA = w * 16 + (l >> 2); if (rowA > 95) rowA = 95;   // w<6 only
  int rB = n0 + (w & 3) * 16 + (l >> 2);
  const unsigned short* srcA1 = A1 + (size_t)(m0 + rowA) * K + g8;
  const unsigned short* srcA2 = A2 + (size_t)(m0 + rowA) * K + g8;
  const unsigned short* srcB1 = B1t + (size_t)rB * K + g8;   // w<4
  const unsigned short* srcB2 = B2t + (size_t)rB * K + g8;   // w>=4

#define D2_STAGE(kt, bi) do { int kk0 = (kt) * 32;                                                                        \
    if (w < 6) {                                                                                                          \
      __builtin_amdgcn_global_load_lds((const unsigned int*)(srcA1 + kk0), (unsigned int*)&As1[bi][0] + w * 256, 16, 0, 0); \
      __builtin_amdgcn_global_load_lds((const unsigned int*)(srcA2 + kk0), (unsigned int*)&As2[bi][0] + w * 256, 16, 0, 0); \
    }                                                                                                                     \
    if (w < 4)                                                                                                            \
      __builtin_amdgcn_global_load_lds((const unsigned int*)(srcB1 + kk0), (unsigned int*)&Bs1[bi][0] + w * 256, 16, 0, 0); \
    else                                                                                                                  \
      __builtin_amdgcn_global_load_lds((const unsigned int*)(srcB2 + kk0), (unsigned int*)&Bs2[bi][0] + (w - 4) * 256, 16, 0, 0); \
  } while (0)

  f32x4 ac1[3] = {};
  f32x4 ac2[3] = {};

  const int NT = K / 32;
  int prm = ((l >> 4) ^ ((l >> 1) & 3)) * 8;
  D2_STAGE(0, 0);
  __syncthreads();
  int cur = 0;
  for (int kt = 0; kt < NT; ++kt) {
    if (kt + 1 < NT) D2_STAGE(kt + 1, cur ^ 1);

    int offB = (wc * 16 + (l & 15)) * 32 + prm;
    bf16x8 af1[3], af2[3];
    #pragma unroll
    for (int i = 0; i < 3; ++i) {
      int off = (wr * 48 + i * 16 + (l & 15)) * 32 + prm;
      af1[i] = *reinterpret_cast<const bf16x8*>(&As1[cur][off]);
      af2[i] = *reinterpret_cast<const bf16x8*>(&As2[cur][off]);
    }
    bf16x8 b1 = *reinterpret_cast<const bf16x8*>(&Bs1[cur][offB]);
    bf16x8 b2 = *reinterpret_cast<const bf16x8*>(&Bs2[cur][offB]);
    #pragma unroll
    for (int i = 0; i < 3; ++i) {
      ac1[i] = __builtin_amdgcn_mfma_f32_16x16x32_bf16(af1[i], b1, ac1[i], 0, 0, 0);
      ac2[i] = __builtin_amdgcn_mfma_f32_16x16x32_bf16(af2[i], b2, ac2[i], 0, 0, 0);
    }
    __syncthreads();
    cur ^= 1;
  }
#undef D2_STAGE

  float alpha = alphap[0];
  float* F0b = F0 + (size_t)bz * sC;
  #pragma unroll
  for (int i = 0; i < 3; ++i) {
    #pragma unroll
    for (int qq = 0; qq < 4; ++qq) {
      int gm = m0 + wr * 48 + i * 16 + (l >> 4) * 4 + qq;
      int gn = n0 + wc * 16 + (l & 15);
      float v = ac1[i][qq] + alpha * ac2[i][qq];
      if (zerodiag && gm == gn) v = 0.f;
      F0b[(size_t)gm * N + gn] = v;
    }
  }
}

// ---------------------------------------------------------------------------
// 4-wave dual-product GEMM, TM=48, N clamped (for E = E0 + gi*Btt@Es, N=96).
// grid (ceil(N/64), M/48, batch), 256 thr.
// ---------------------------------------------------------------------------
__global__ __launch_bounds__(256)
void mfma_dualE(const unsigned short* __restrict__ A1,
                const unsigned short* __restrict__ B1t,
                const unsigned short* __restrict__ A2,
                const unsigned short* __restrict__ B2t,
                const float* __restrict__ alphap, float* __restrict__ F0,
                int M, int N, int K1, int K2,
                long sA1, long sB1, long sA2, long sB2, long sC)
{
  __shared__ unsigned short As1[2][1536], Bs1[2][2048];
  __shared__ unsigned short As2[2][1536], Bs2[2][2048];

  int nx = gridDim.x, ny = gridDim.y;
  int nwg = nx * ny * gridDim.z;
  int lin = blockIdx.x + nx * (blockIdx.y + ny * blockIdx.z);
  int sw = xcd_swz(lin, nwg);
  int bxi = sw % nx; int rest = sw / nx;
  int byi = rest % ny; int bz = rest / ny;

  A1  += (size_t)bz * sA1;
  B1t += (size_t)bz * sB1;
  A2  += (size_t)bz * sA2;
  B2t += (size_t)bz * sB2;

  int tid = threadIdx.x;
  int w = tid >> 6, l = tid & 63;
  int m0 = byi * 48, n0 = bxi * 64;

  int g8 = (((l & 3) ^ ((l >> 3) & 3))) * 8;
  int rowA = w * 16 + (l >> 2); if (rowA > 47) rowA = 47;   // w<3 only
  int rB = n0 + w * 16 + (l >> 2); if (rB > N - 1) rB = N - 1;
  const unsigned short* srcA1 = A1 + (size_t)(m0 + rowA) * K1 + g8;
  const unsigned short* srcA2 = A2 + (size_t)(m0 + rowA) * K2 + g8;
  const unsigned short* srcB1 = B1t + (size_t)rB * K1 + g8;
  const unsigned short* srcB2 = B2t + (size_t)rB * K2 + g8;

#define DE_STAGE(kt, bi) do { int kk0 = (kt) * 32;                                                                        \
    if (w < 3) {                                                                                                          \
      __builtin_amdgcn_global_load_lds((const unsigned int*)(srcA1 + kk0), (unsigned int*)&As1[bi][0] + w * 256, 16, 0, 0); \
      __builtin_amdgcn_global_load_lds((const unsigned int*)(srcA2 + kk0), (unsigned int*)&As2[bi][0] + w * 256, 16, 0, 0); \
    }                                                                                                                     \
    __builtin_amdgcn_global_load_lds((const unsigned int*)(srcB1 + kk0), (unsigned int*)&Bs1[bi][0] + w * 256, 16, 0, 0);   \
    __builtin_amdgcn_global_load_lds((const unsigned int*)(srcB2 + kk0), (unsigned int*)&Bs2[bi][0] + w * 256, 16, 0, 0);   \
  } while (0)

  f32x4 ac1[3] = {};
  f32x4 ac2[3] = {};

  const int NT = K1 / 32;   // K1 == K2 at the call site (768)
  int prm = ((l >> 4) ^ ((l >> 1) & 3)) * 8;
  DE_STAGE(0, 0);
  __syncthreads();
  int cur = 0;
  for (int kt = 0; kt < NT; ++kt) {
    if (kt + 1 < NT) DE_STAGE(kt + 1, cur ^ 1);

    int offB = (w * 16 + (l & 15)) * 32 + prm;
    bf16x8 af1[3], af2[3];
    #pragma unroll
    for (int i = 0; i < 3; ++i) {
      int off = (i * 16 + (l & 15)) * 32 + prm;
      af1[i] = *reinterpret_cast<const bf16x8*>(&As1[cur][off]);
      af2[i] = *reinterpret_cast<const bf16x8*>(&As2[cur][off]);
    }
    bf16x8 b1 = *reinterpret_cast<const bf16x8*>(&Bs1[cur][offB]);
    bf16x8 b2 = *reinterpret_cast<const bf16x8*>(&Bs2[cur][offB]);
    #pragma unroll
    for (int i = 0; i < 3; ++i) {
      ac1[i] = __builtin_amdgcn_mfma_f32_16x16x32_bf16(af1[i], b1, ac1[i], 0, 0, 0);
      ac2[i] = __builtin_amdgcn_mfma_f32_16x16x32_bf16(af2[i], b2, ac2[i], 0, 0, 0);
    }
    __syncthreads();
    cur ^= 1;
  }
#undef DE_STAGE

  float alpha = alphap[0];
  float* F0b = F0 + (size_t)bz * sC;
  #pragma unroll
  for (int i = 0; i < 3; ++i) {
    #pragma unroll
    for (int qq = 0; qq < 4; ++qq) {
      int gm = m0 + i * 16 + (l >> 4) * 4 + qq;
      int gn = n0 + w * 16 + (l & 15);
      if (gn >= N) continue;
      float v = ac1[i][qq] + alpha * ac2[i][qq];
      F0b[(size_t)gm * N + gn] = v;
    }
  }
}

// ---------------------------------------------------------------------------
// Fused dual-B MFMA SFU GEMM, 96x64 tile, double-buffered, swizzled LDS,
// 512 thr / 8 waves (2x4, wave tile 48x16 -- R5-proven), XCD-chunked blocks.
// grid (12, 64) = 768 wg. K=2304 logical: kt<24 sources rows from Xseg
// (bf16 activation, stride 768), kt>=24 from Mc2 (stride 1536 = [f | x*f]).
// ---------------------------------------------------------------------------
__global__ __launch_bounds__(512)
void sfu_mfma(const unsigned short* __restrict__ Mc2,
              const unsigned short* __restrict__ Xseg,
              const unsigned short* __restrict__ Brt,
              const unsigned short* __restrict__ Bgt,
              const float* __restrict__ Xres, float* __restrict__ Z,
              unsigned short* __restrict__ Zb)
{
  __shared__ unsigned short As[2][3072];
  __shared__ unsigned short Brs[2][2048];
  __shared__ unsigned short Bgs[2][2048];
  const int K = 2304;
  const int NT = 72;

  int nx = gridDim.x, ny = gridDim.y;
  int nwg = nx * ny;
  int lin = blockIdx.x + nx * blockIdx.y;
  int sw = xcd_swz(lin, nwg);
  int bxi = sw % nx; int byi = sw / nx;

  int tid = threadIdx.x;
  int w = tid >> 6, l = tid & 63;
  int m0 = byi * 96, n0 = bxi * 64;
  int wr = w >> 2, wc = w & 3;

  int g8 = (((l & 3) ^ ((l >> 3) & 3))) * 8;
  int rowA = w * 16 + (l >> 2); if (rowA > 95) rowA = 95;   // used only by w<6
  int rB = n0 + (w & 3) * 16 + (l >> 2);
  const unsigned short* srcX = Xseg + (size_t)(m0 + rowA) * 768 + g8;   // kt<24
  const unsigned short* srcM = Mc2  + (size_t)(m0 + rowA) * 1536 + g8;  // kt>=24
  const unsigned short* srcR = Brt + (size_t)rB * K + g8;   // w<4
  const unsigned short* srcG = Bgt + (size_t)rB * K + g8;   // w>=4

#define SFU_STAGE(kt, bi) do {                                                                                           \
    const unsigned short* aptr = ((kt) < 24) ? (srcX + (kt) * 32) : (srcM + ((kt) - 24) * 32);                           \
    int kk0 = (kt) * 32;                                                                                                 \
    if (w < 6)                                                                                                           \
      __builtin_amdgcn_global_load_lds((const unsigned int*)aptr, (unsigned int*)&As[bi][0]  + w * 256, 16, 0, 0);        \
    if (w < 4)                                                                                                           \
      __builtin_amdgcn_global_load_lds((const unsigned int*)(srcR + kk0), (unsigned int*)&Brs[bi][0] + w * 256, 16, 0, 0); \
    if (w >= 4)                                                                                                          \
      __builtin_amdgcn_global_load_lds((const unsigned int*)(srcG + kk0), (unsigned int*)&Bgs[bi][0] + (w - 4) * 256, 16, 0, 0); \
  } while (0)

  f32x4 aR[3] = {};
  f32x4 aG[3] = {};

  int prm = ((l >> 4) ^ ((l >> 1) & 3)) * 8;
  SFU_STAGE(0, 0);
  __syncthreads();
  int cur = 0;
  for (int kt = 0; kt < NT; ++kt) {
    if (kt + 1 < NT) SFU_STAGE(kt + 1, cur ^ 1);

    bf16x8 af[3];
    #pragma unroll
    for (int i = 0; i < 3; ++i) {
      int off = (wr * 48 + i * 16 + (l & 15)) * 32 + prm;
      af[i] = *reinterpret_cast<const bf16x8*>(&As[cur][off]);
    }
    int offB = (wc * 16 + (l & 15)) * 32 + prm;
    bf16x8 br = *reinterpret_cast<const bf16x8*>(&Brs[cur][offB]);
    bf16x8 bg = *reinterpret_cast<const bf16x8*>(&Bgs[cur][offB]);
    #pragma unroll
    for (int i = 0; i < 3; ++i) {
      aR[i] = __builtin_amdgcn_mfma_f32_16x16x32_bf16(af[i], br, aR[i], 0, 0, 0);
      aG[i] = __builtin_amdgcn_mfma_f32_16x16x32_bf16(af[i], bg, aG[i], 0, 0, 0);
    }
    __syncthreads();
    cur ^= 1;
  }
#undef SFU_STAGE

  #pragma unroll
  for (int i = 0; i < 3; ++i) {
    #pragma unroll
    for (int qq = 0; qq < 4; ++qq) {
      int gm = m0 + wr * 48 + i * 16 + (l >> 4) * 4 + qq;
      int gn = n0 + wc * 16 + (l & 15);
      float r = fmaxf(aR[i][qq], 0.f);
      float g = 1.0f / (1.0f + expf(-aG[i][qq]));
      float xv = Xres[(size_t)gm * 768 + gn];
      float z = r * g + (1.0f - g) * xv;
      Z[(size_t)gm * 768 + gn] = z;
      if (Zb) Zb[(size_t)gm * 768 + gn] = f2bf(z);
    }
  }
}

// ---------------------------------------------------------------------------
// host side
// ---------------------------------------------------------------------------
static void launch_mfma1(const unsigned short* A, const unsigned short* Bt,
                         const float* bias, const float* alphap, const float* C0,
                         float* F0, unsigned short* O0,
                         int M, int N, int K, long sA, long sB, long sC0, long sC,
                         int relu, int zd, int batch, int tm, hipStream_t s,
                         const unsigned short* xcat = nullptr, unsigned short* mco = nullptr)
{
  dim3 g((N + 63) / 64, M / tm, batch);
  if (tm == 48)
    mfma_gemm<1, 4><<<g, 256, 0, s>>>(A, Bt, nullptr, bias, nullptr, alphap, C0,
                                      F0, nullptr, O0, nullptr, M, N, K, sA, sB, sC0, sC, relu, zd,
                                      xcat, mco);
  else
    mfma_gemm<1, 8><<<g, 512, 0, s>>>(A, Bt, nullptr, bias, nullptr, alphap, C0,
                                      F0, nullptr, O0, nullptr, M, N, K, sA, sB, sC0, sC, relu, zd,
                                      xcat, mco);
}

static void launch_mfma2(const unsigned short* A, const unsigned short* Bt0,
                         const unsigned short* Bt1, const float* bias0, const float* bias1,
                         unsigned short* O0, unsigned short* O1,
                         int M, int N, int K, long sA, long sB,
                         int relu, int batch, hipStream_t s)
{
  dim3 g((N + 63) / 64, M / 96, batch);
  mfma_gemm<2, 8><<<g, 512, 0, s>>>(A, Bt0, Bt1, bias0, bias1, nullptr, nullptr,
                                    nullptr, nullptr, O0, O1, M, N, K, sA, sB, 0, sA,
                                    relu, 0, nullptr, nullptr);
}

extern "C" void kernel_launch(void* const* d_in, const int* in_sizes, int n_in,
                              void* d_out, int out_size, void* d_ws, size_t ws_size,
                              hipStream_t stream)
{
  const int b = 8, c = 768, q = 96, d = 768, T = 2;
  const float* U   = (const float*)d_in[0];
  const float* V   = (const float*)d_in[1];
  const int*   Um  = (const int*)d_in[2];
  const int*   Vm  = (const int*)d_in[3];
  const float* Wu  = (const float*)d_in[4];
  const float* bu  = (const float*)d_in[5];
  const float* Wv  = (const float*)d_in[6];
  const float* bv  = (const float*)d_in[7];
  const float* Wri = (const float*)d_in[8];
  const float* Wgi = (const float*)d_in[9];
  const float* gi  = (const float*)d_in[10];
  const float* W1  = (const float*)d_in[11];
  const float* b1  = (const float*)d_in[12];
  const float* W2  = (const float*)d_in[13];
  const float* b2  = (const float*)d_in[14];
  const float* Wrs = (const float*)d_in[15];
  const float* Wgs = (const float*)d_in[16];
  const float* gs  = (const float*)d_in[17];
  float* out = (float*)d_out;

  const size_t big = (size_t)b * c * d;   // 4718592 == b*c*c
  const size_t smE = (size_t)b * c * q;   // 589824 == b*q*d
  float* ws   = (float*)d_ws;
  float* xbuf = ws + 0 * big;
  float* h    = ws + 1 * big;
  float* Bm   = ws + 2 * big;
  float* t1   = ws + 3 * big;             // Mc2 bf16 (6144x1536) / H1b+H2b bf16
  float* t2   = ws + 4 * big;             // XB1 bf16 (h)
  float* t3   = ws + 5 * big;             // XB0 bf16 (x/z) + t3h2 (Btt)
  float* t4   = ws + 6 * big;             // SFU Wt bf16 (4 slices, 14.2 MB)
  float* Ebuf = ws + 7 * big;             // persistent E (b,c,q)
  float* E0b  = Ebuf + smE;               // (unused)
  float* Esb  = E0b + smE;                // E^T f32 scratch
  float* spare = Esb + smE;               // colsm stats
  float* slotE = spare + smE;             // big/2 f32: B1sT b16 / hTb16
  float* WTf  = slotE + big / 2;          // weight + activation bf16 region

  unsigned short* Mc2 = (unsigned short*)t1;           // 6144x1536 bf16 (= t1)
  unsigned short* Wt  = (unsigned short*)t4;           // SFU weights bf16 (4 folded slices)
  unsigned short* t1h = (unsigned short*)t1;           // H1b home
  unsigned short* XB0 = (unsigned short*)t3;           // x / z bf16
  unsigned short* XB1 = (unsigned short*)t2;           // h bf16
  unsigned short* t3h2 = XB0 + big;                    // Btt bf16 (persists)
  unsigned short* slotEb = (unsigned short*)slotE;     // B1sT bf16 / hT bf16
  unsigned short* H1b = t1h;
  unsigned short* H2b = H1b + big;
  float* SMst = spare;                                 // 8*12*12*64 floats
  float* SSst = spare + 73728;
  unsigned short* WuT = (unsigned short*)WTf;
  unsigned short* WvT  = WuT  + (size_t)d * d;
  unsigned short* W1T  = WvT  + (size_t)d * d;
  unsigned short* W2T  = W1T  + (size_t)d * d;
  unsigned short* Vb16 = W2T  + (size_t)d * d;         // (b*q, d) bf16
  unsigned short* Qtbb = Vb16 + smE;                   // (b, q, d) bf16
  unsigned short* VTb  = Qtbb + smE;                   // (b, d, q) bf16
  unsigned short* EsTb = VTb  + smE;                   // (b, q, c) bf16

  const long cd = (long)c * d, cq = (long)c * q, qd = (long)q * d, cc = (long)c * c;
  const size_t dd = (size_t)d * d;
  const size_t wslice = (size_t)768 * 2304;
  const int cast_big = (int)(big / 8);
  (void)ws_size; (void)E0b;

  const float* x = U;
  for (int t = 0; t < T; ++t) {
    const float* Writ = Wri + (size_t)t * 4 * dd;
    const float* Wgit = Wgi + (size_t)t * 4 * dd;
    const float* Wrst = Wrs + (size_t)t * 4 * dd;
    const float* Wgst = Wgs + (size_t)t * 4 * dd;

    // -- prep: 8 weight transposes; at t>0 also colsm_emit (B1sT) in the
    //    same launch (independent of the weight work; overlaps) --
    int prep_blocks = (t == 0) ? 2304 : (2304 + 1152);
    fused_prep<<<dim3(prep_blocks), 256, 0, stream>>>(
        Writ, Wgit, Wrst, Wgst,
        Wu + t * dd, Wv + t * dd, W1 + t * dd, W2 + t * dd, Wt, WuT,
        Bm, Um, SMst, SSst, slotEb);
    if (t == 0) {
      cast_bf16<<<dim3((int)(smE / 8 / 256)), 256, 0, stream>>>(V, Vb16, (int)(smE / 8));
      transpV<<<dim3(12, 2, b), 256, 0, stream>>>(V, VTb);
      cast_bf16<<<dim3(cast_big / 256), 256, 0, stream>>>(x, XB0, cast_big);  // xb16 (U)
    }
    // t=1: XB0 already holds z bf16 from stage-0 step-13 dual write

    // 1+2 merged: Ctb = relu(x@Wu+bu) -> t1h  AND  Qtb = relu(V@Wv+bv) -> Qtbb
    mfma_relu_pair<<<dim3(12, 72), 512, 0, stream>>>(XB0, WuT, bu + t * d, t1h,
                                                     Vb16, WvT, bv + t * d, Qtbb);
    if (t == 0) {
      // 3. E0 = Ctb @ Qtb^T -> Ebuf (MFMA, N=96 clamped, TM=48)
      launch_mfma1(t1h, Qtbb, nullptr, nullptr, nullptr, Ebuf, nullptr,
                   c, q, d, cd, qd, 0, cq, 0, 0, b, 48, stream);
    } else {
      // 4a. EsT bf16 = row-softmax over c of (prev) E^T  [reads old Ebuf]
      transp_f32<<<dim3(2, 12, b), 256, 0, stream>>>(Ebuf, Esb, c, q, cq, cq);
      softmax_row_mask<<<dim3(q, b), 256, 0, stream>>>(Esb, Um, nullptr, EsTb, q, c);
      // 3+4c fused: E = Ctb@Qtb^T + gi * Btt_prev@Es  -> Ebuf (dual-product)
      mfma_dualE<<<dim3(2, 16, b), 256, 0, stream>>>(t1h, Qtbb, t3h2, EsTb,
                                                     gi + t, Ebuf,
                                                     c, q, d, c, cd, qd, cc, cq, cq);
    }
    // 5+6 fused: Mc2 = [qctx | x*qctx], qctx = rowsoftmax_Vm(E) @ V
    qctx_fused<<<dim3(12, 8, b), 512, 0, stream>>>(Ebuf, Vm, VTb, XB0, Mc2);
    // 7. h = SFU(x, qctx): seg0 streamed from XB0; writes h f32 + hb16 (XB1)
    sfu_mfma<<<dim3(12, 64), 512, 0, stream>>>(Mc2, XB0, Wt, Wt + wslice, x, h, XB1);
    // 8. H1,H2 dual-B (A = hb16 = XB1) -> bf16 H1b,H2b (overwrites Mc2 - dead)
    launch_mfma2(XB1, W1T, W2T, b1 + t * d, b2 + t * d, H1b, H2b,
                 b * c, d, d, 0, 0, 1, 1, stream);
    // 9/10. B0 and B carry
    if (t == 0) {
      launch_mfma1(H1b, H2b, nullptr, nullptr, nullptr, Bm, nullptr,
                   c, c, d, cd, cd, 0, cc, 0, 1, b, 96, stream);
    } else {
      // B1sT already in slotEb (fused_prep emit); Btt_prev in t3h2
      mfma_dual2<<<dim3(12, 8, b), 512, 0, stream>>>(H1b, H2b, t3h2, slotEb,
                                                     gs + t, Bm,
                                                     c, c, d, cd, cd, cc, cc, cc, 1);
    }
    // 11+12a (+ next-stage colsm_stats at t<T-1), all independent, ONE launch:
    //   softmax(Bm)->Btt(t3h2) || transp(XB1)->hT(slotEb) || stats(Bm)->SM/SS
    int tail_blocks = 6144 + 1152 + ((t < T - 1) ? 1152 : 0);
    fused_tail<<<dim3(tail_blocks), 256, 0, stream>>>(Bm, Um, t3h2, XB1, slotEb,
                                                      SMst, SSst);
    // 12b. hctx GEMM with Mc2-concat epilogue: Mc2 = [hctx | h*hctx]
    launch_mfma1(t3h2, slotEb, nullptr, nullptr, nullptr, nullptr, nullptr,
                 c, d, c, cc, cd, 0, cd, 0, 0, b, 96, stream, XB1, Mc2);
    // 13. Z = SFU(h, hctx): seg0 streamed from XB1; dual-write z bf16 -> XB0
    float* zdst = (t == T - 1) ? out : xbuf;
    unsigned short* zb16 = (t == T - 1) ? nullptr : XB0;
    sfu_mfma<<<dim3(12, 64), 512, 0, stream>>>(Mc2, XB1, Wt + 2 * wslice, Wt + 3 * wslice,
                                               h, zdst, zb16);

    x = xbuf;
  }
}